// Round 11
// baseline (700.697 us; speedup 1.0000x reference)
//
#include <hip/hip_runtime.h>
#include <math.h>

static constexpr int S    = 41;
static constexpr int DIN  = 1280;
static constexpr int DOUT = 1024;
static constexpr int HEADS = 4;
static constexpr int HC   = 256;

typedef __attribute__((ext_vector_type(4))) float f32x4;
typedef __attribute__((ext_vector_type(8))) short short8;

__device__ __forceinline__ ushort f2bf(float f) {
  uint u = __float_as_uint(f);
  uint r = u + 0x7fffu + ((u >> 16) & 1u);   // RNE
  return (ushort)(r >> 16);
}
__device__ __forceinline__ float bf2f(ushort u) {
  return __uint_as_float(((uint)u) << 16);
}

__device__ __forceinline__ void gload16(const ushort* g, ushort* l) {
  __builtin_amdgcn_global_load_lds((const __attribute__((address_space(1))) void*)g,
                                   (__attribute__((address_space(3))) void*)l, 16, 0, 0);
}

// ---------------- reduction helpers ----------------

__device__ __forceinline__ float warpReduceSum(float v) {
#pragma unroll
  for (int off = 32; off; off >>= 1) v += __shfl_down(v, off);
  return v;
}

__device__ __forceinline__ void blockReduce6(float* v) {
  __shared__ float red6[6][4];
  int w = threadIdx.x >> 6, lane = threadIdx.x & 63;
#pragma unroll
  for (int r = 0; r < 6; ++r) v[r] = warpReduceSum(v[r]);
  __syncthreads();
  if (lane == 0) {
#pragma unroll
    for (int r = 0; r < 6; ++r) red6[r][w] = v[r];
  }
  __syncthreads();
#pragma unroll
  for (int r = 0; r < 6; ++r)
    v[r] = red6[r][0] + red6[r][1] + red6[r][2] + red6[r][3];
}

__device__ __forceinline__ void blockReduce3v(float* v) {
  __shared__ float red3[3][4];
  int w = threadIdx.x >> 6, lane = threadIdx.x & 63;
#pragma unroll
  for (int r = 0; r < 3; ++r) v[r] = warpReduceSum(v[r]);
  __syncthreads();
  if (lane == 0) {
#pragma unroll
    for (int r = 0; r < 3; ++r) red3[r][w] = v[r];
  }
  __syncthreads();
#pragma unroll
  for (int r = 0; r < 3; ++r)
    v[r] = red3[r][0] + red3[r][1] + red3[r][2] + red3[r][3];
}

// ---------------- fused x->bf16 convert + sigmoid row gate ----------------

__global__ __launch_bounds__(256) void cvtsig_kernel(
    const float4* __restrict__ x, const float* __restrict__ att_w,
    const float* __restrict__ att_b, ushort4* __restrict__ xb, float* __restrict__ sig)
{
  int row  = blockIdx.x * 4 + (threadIdx.x >> 6);
  int lane = threadIdx.x & 63;
  const float4* xr = x + (size_t)row * (DIN / 4);
  const float4* wr = (const float4*)att_w;
  ushort4* xo = xb + (size_t)row * (DIN / 4);
  float acc = 0.f;
#pragma unroll
  for (int k = 0; k < DIN / 4 / 64; ++k) {   // 5
    float4 a = xr[lane + k * 64];
    float4 w = wr[lane + k * 64];
    acc += a.x * w.x + a.y * w.y + a.z * w.z + a.w * w.w;
    ushort4 o;
    o.x = f2bf(a.x); o.y = f2bf(a.y); o.z = f2bf(a.z); o.w = f2bf(a.w);
    xo[lane + k * 64] = o;
  }
  acc = warpReduceSum(acc);
  if (lane == 0) sig[row] = 1.f / (1.f + expf(-(acc + att_b[0])));
}

// ---------------- weight converts ----------------

__global__ __launch_bounds__(256) void wcvt_kernel(const float* __restrict__ W,
                                                   ushort* __restrict__ out,
                                                   int K, int N, int ostride, int koff) {
  __shared__ float t[32][33];
  int n0 = blockIdx.x * 32, k0 = blockIdx.y * 32;
  int tx = threadIdx.x & 31, ty = threadIdx.x >> 5;
#pragma unroll
  for (int r = 0; r < 4; ++r) {
    int k = ty + r * 8;
    t[k][tx] = W[(size_t)(k0 + k) * N + n0 + tx];
  }
  __syncthreads();
#pragma unroll
  for (int r = 0; r < 4; ++r) {
    int nn = ty + r * 8;
    out[(size_t)(n0 + nn) * ostride + koff + k0 + tx] = f2bf(t[tx][nn]);
  }
}

// wpw[n][k] = n<41 ? bf16(w2[k][n]) : 0   (128 x 512)
__global__ __launch_bounds__(256) void w2cvt_kernel(const float* __restrict__ w2,
                                                    ushort* __restrict__ wpw) {
  int idx = blockIdx.x * 256 + threadIdx.x;
  int n = idx >> 9, k = idx & 511;
  wpw[idx] = (n < S) ? f2bf(w2[(size_t)k * S + n]) : (ushort)0;
}

// ---------------- shared epilogue descriptor ----------------

struct Epi {
  void* dst[5];
  const float* bias[5];
  int nend[5];
  int ld[5];
  int relu[5];
  const float* rs;             // rowscale, branch 0 only
};

// ---------------- 256x256-tile bf16 MFMA GEMM: 8 waves, 3-stage ring, counted vmcnt ----------------
// Same sync structure as the verified 128^2 ring; only tile geometry scaled.
// LDS chunk-swizzle (rule #21): linear gload_lds dest + inverse-permuted GLOBAL
// source chunk + permuted READ chunk.

__global__ __launch_bounds__(512, 1) void gemm256(
    const ushort* __restrict__ A, const ushort* __restrict__ Bt, int K, int nb, Epi e)
{
  __shared__ __align__(16) ushort As[3][256 * 32];   // 3 x 16KB
  __shared__ __align__(16) ushort Bs[3][256 * 32];   // 3 x 16KB

  const int bid = blockIdx.x;
  const int bm  = (bid / nb) * 256;     // bn-fastest: consecutive blocks share A panel
  const int bn  = (bid % nb) * 256;

  const int tid  = threadIdx.x;
  const int w    = tid >> 6;            // 0..7
  const int lane = tid & 63;
  const int l16  = lane & 15;
  const int l4   = lane >> 4;
  const int wr   = w >> 2;              // 0..1  -> 128-row strip
  const int wc   = w & 3;               // 0..3  -> 64-col strip
  const int m0   = wr * 128;
  const int n0   = wc * 64;

  // staging: wave w stages rows [w*32, w*32+32) of both A and B tiles
  const int rloc = lane >> 2;           // 0..15
  const int cpos = lane & 3;
  const int cdat = (cpos - (rloc >> 1)) & 3;    // inverse-permuted source chunk
  const int srow = w * 32 + rloc;
  const int scol = cdat * 8;

  f32x4 acc[8][4];
#pragma unroll
  for (int i = 0; i < 8; ++i)
#pragma unroll
    for (int j = 0; j < 4; ++j) acc[i][j] = (f32x4)0.f;

  const ushort* pA0 = A  + (size_t)(bm + srow) * K + scol;
  const ushort* pA1 = A  + (size_t)(bm + srow + 16) * K + scol;
  const ushort* pB0 = Bt + (size_t)(bn + srow) * K + scol;
  const ushort* pB1 = Bt + (size_t)(bn + srow + 16) * K + scol;

  auto stage = [&](int buf, int kt) {
    gload16(pA0 + kt, &As[buf][w * 1024]);
    gload16(pA1 + kt, &As[buf][w * 1024 + 512]);
    gload16(pB0 + kt, &Bs[buf][w * 1024]);
    gload16(pB1 + kt, &Bs[buf][w * 1024 + 512]);
  };

  // read-side swizzled chunk
  const int rchunk = ((l4 + (l16 >> 1)) & 3) * 8;

  const int nsteps = K >> 5;            // 40 for K=1280
  stage(0, 0); stage(1, 32); stage(2, 64);   // 12 vm-ops/thread in flight

  for (int t = 0; t < nsteps; ++t) {
    if (t == 0)                asm volatile("s_waitcnt vmcnt(8)" ::: "memory");
    else if (t == nsteps - 1)  asm volatile("s_waitcnt vmcnt(0)" ::: "memory");
    else                       asm volatile("s_waitcnt vmcnt(4)" ::: "memory");
    __builtin_amdgcn_s_barrier();
    asm volatile("" ::: "memory");

    if (t >= 1 && t + 2 < nsteps) stage((t + 2) % 3, (t + 2) * 32);

    const int cur = t % 3;
    short8 a[8], b[4];
#pragma unroll
    for (int i = 0; i < 8; ++i)
      a[i] = *reinterpret_cast<const short8*>(&As[cur][(m0 + i * 16 + l16) * 32 + rchunk]);
#pragma unroll
    for (int j = 0; j < 4; ++j)
      b[j] = *reinterpret_cast<const short8*>(&Bs[cur][(n0 + j * 16 + l16) * 32 + rchunk]);
    __builtin_amdgcn_s_setprio(1);
#pragma unroll
    for (int i = 0; i < 8; ++i)
#pragma unroll
      for (int j = 0; j < 4; ++j)
        acc[i][j] = __builtin_amdgcn_mfma_f32_16x16x32_bf16(a[i], b[j], acc[i][j], 0, 0, 0);
    __builtin_amdgcn_s_setprio(0);
  }

  void* dstv; const float* bias; const float* rs = nullptr; int ldc, cb, relu;
  if (bn < e.nend[0])      { dstv = e.dst[0]; ldc = e.ld[0]; cb = bn;             bias = e.bias[0]; relu = e.relu[0]; rs = e.rs; }
  else if (bn < e.nend[1]) { dstv = e.dst[1]; ldc = e.ld[1]; cb = bn - e.nend[0]; bias = e.bias[1]; relu = e.relu[1]; }
  else if (bn < e.nend[2]) { dstv = e.dst[2]; ldc = e.ld[2]; cb = bn - e.nend[1]; bias = e.bias[2]; relu = e.relu[2]; }
  else if (bn < e.nend[3]) { dstv = e.dst[3]; ldc = e.ld[3]; cb = bn - e.nend[2]; bias = e.bias[3]; relu = e.relu[3]; }
  else                     { dstv = e.dst[4]; ldc = e.ld[4]; cb = bn - e.nend[3]; bias = e.bias[4]; relu = e.relu[4]; }

#pragma unroll
  for (int i = 0; i < 8; ++i) {
    int mbase = bm + m0 + i * 16 + l4 * 4;
    float rsv[4];
#pragma unroll
    for (int r = 0; r < 4; ++r) rsv[r] = rs ? rs[mbase + r] : 1.f;
#pragma unroll
    for (int j = 0; j < 4; ++j) {
      int col = cb + n0 + j * 16 + l16;
      float bv = bias ? bias[col] : 0.f;
#pragma unroll
      for (int r = 0; r < 4; ++r) {
        float t = acc[i][j][r] * rsv[r] + bv;
        if (relu) t = fmaxf(t, 0.f);
        ((ushort*)dstv)[(size_t)(mbase + r) * ldc + col] = f2bf(t);
      }
    }
  }
}

// ---------------- 128x128 bf16 MFMA GEMM (kept for fp2: N=128) ----------------

template<bool F32OUT>
__global__ __launch_bounds__(256) void gemm_bf16(
    const ushort* __restrict__ A, const ushort* __restrict__ Bt, int K, int nb, Epi e)
{
  __shared__ __align__(16) ushort As[3][128 * 32];
  __shared__ __align__(16) ushort Bs[3][128 * 32];

  const int bid = blockIdx.x;
  const int bm  = (bid / nb) * 128;
  const int bn  = (bid % nb) * 128;

  const int tid  = threadIdx.x;
  const int w    = tid >> 6;
  const int lane = tid & 63;
  const int l16  = lane & 15;
  const int l4   = lane >> 4;
  const int m0   = (w >> 1) * 64;
  const int n0   = (w & 1) * 64;

  const int rloc = lane >> 2;
  const int cpos = lane & 3;
  const int cdat = (cpos - (rloc >> 1)) & 3;
  const int srow = w * 32 + rloc;
  const int scol = cdat * 8;

  f32x4 acc[4][4];
#pragma unroll
  for (int i = 0; i < 4; ++i)
#pragma unroll
    for (int j = 0; j < 4; ++j) acc[i][j] = (f32x4)0.f;

  const ushort* pA0 = A  + (size_t)(bm + srow) * K + scol;
  const ushort* pA1 = A  + (size_t)(bm + srow + 16) * K + scol;
  const ushort* pB0 = Bt + (size_t)(bn + srow) * K + scol;
  const ushort* pB1 = Bt + (size_t)(bn + srow + 16) * K + scol;

  auto stage = [&](int buf, int kt) {
    gload16(pA0 + kt, &As[buf][w * 1024]);
    gload16(pA1 + kt, &As[buf][w * 1024 + 512]);
    gload16(pB0 + kt, &Bs[buf][w * 1024]);
    gload16(pB1 + kt, &Bs[buf][w * 1024 + 512]);
  };

  const int rchunk = ((l4 + (l16 >> 1)) & 3) * 8;

  const int nsteps = K >> 5;
  stage(0, 0); stage(1, 32); stage(2, 64);

  for (int t = 0; t < nsteps; ++t) {
    if (t == 0)                asm volatile("s_waitcnt vmcnt(8)" ::: "memory");
    else if (t == nsteps - 1)  asm volatile("s_waitcnt vmcnt(0)" ::: "memory");
    else                       asm volatile("s_waitcnt vmcnt(4)" ::: "memory");
    __builtin_amdgcn_s_barrier();
    asm volatile("" ::: "memory");

    if (t >= 1 && t + 2 < nsteps) stage((t + 2) % 3, (t + 2) * 32);

    const int cur = t % 3;
    short8 a[4], b[4];
#pragma unroll
    for (int i = 0; i < 4; ++i)
      a[i] = *reinterpret_cast<const short8*>(&As[cur][(m0 + i * 16 + l16) * 32 + rchunk]);
#pragma unroll
    for (int j = 0; j < 4; ++j)
      b[j] = *reinterpret_cast<const short8*>(&Bs[cur][(n0 + j * 16 + l16) * 32 + rchunk]);
    __builtin_amdgcn_s_setprio(1);
#pragma unroll
    for (int i = 0; i < 4; ++i)
#pragma unroll
      for (int j = 0; j < 4; ++j)
        acc[i][j] = __builtin_amdgcn_mfma_f32_16x16x32_bf16(a[i], b[j], acc[i][j], 0, 0, 0);
    __builtin_amdgcn_s_setprio(0);
  }

  void* dstv; const float* bias; const float* rs = nullptr; int ldc, cb, relu;
  if (bn < e.nend[0])      { dstv = e.dst[0]; ldc = e.ld[0]; cb = bn;             bias = e.bias[0]; relu = e.relu[0]; rs = e.rs; }
  else if (bn < e.nend[1]) { dstv = e.dst[1]; ldc = e.ld[1]; cb = bn - e.nend[0]; bias = e.bias[1]; relu = e.relu[1]; }
  else if (bn < e.nend[2]) { dstv = e.dst[2]; ldc = e.ld[2]; cb = bn - e.nend[1]; bias = e.bias[2]; relu = e.relu[2]; }
  else if (bn < e.nend[3]) { dstv = e.dst[3]; ldc = e.ld[3]; cb = bn - e.nend[2]; bias = e.bias[3]; relu = e.relu[3]; }
  else                     { dstv = e.dst[4]; ldc = e.ld[4]; cb = bn - e.nend[3]; bias = e.bias[4]; relu = e.relu[4]; }

#pragma unroll
  for (int i = 0; i < 4; ++i) {
    int mbase = bm + m0 + i * 16 + l4 * 4;
    float rsv[4];
#pragma unroll
    for (int r = 0; r < 4; ++r) rsv[r] = rs ? rs[mbase + r] : 1.f;
#pragma unroll
    for (int j = 0; j < 4; ++j) {
      int col = cb + n0 + j * 16 + l16;
      float bv = bias ? bias[col] : 0.f;
#pragma unroll
      for (int r = 0; r < 4; ++r) {
        float t = acc[i][j][r] * rsv[r] + bv;
        if (relu) t = fmaxf(t, 0.f);
        if (F32OUT) ((float*)dstv)[(size_t)(mbase + r) * ldc + col] = t;
        else        ((ushort*)dstv)[(size_t)(mbase + r) * ldc + col] = f2bf(t);
      }
    }
  }
}

// ---------------- pwprep: softmax rows + prefix-mean rows -> global pc (f32) ----------------

__global__ __launch_bounds__(256) void pwprep_kernel(
    const float* __restrict__ fp2, const float* __restrict__ fp_b2,
    float* __restrict__ pc)
{
  int b = blockIdx.x;
  int tid = threadIdx.x, wv = tid >> 6, lane = tid & 63;
  __shared__ float pws[S][S];
  for (int i = wv; i < S; i += 4) {
    float v = (lane < S) ? (fp2[(size_t)(b * S + i) * 128 + lane] + fp_b2[lane]) : -1e30f;
    float m = v;
#pragma unroll
    for (int off = 32; off; off >>= 1) m = fmaxf(m, __shfl_xor(m, off));
    float e = (lane < S) ? expf(v - m) : 0.f;
    float sum = e;
#pragma unroll
    for (int off = 32; off; off >>= 1) sum += __shfl_xor(sum, off);
    if (lane < S) {
      float p = e / sum;
      pws[i][lane] = p;
      pc[((size_t)b * S + i) * 128 + lane] = p;
    }
  }
  __syncthreads();
  if (tid < S) {
    float run = 0.f;
    for (int i = 0; i < S; ++i) {
      pc[((size_t)b * S + i) * 128 + 64 + tid] = (i > 0) ? run / (float)i : 0.f;
      run += pws[i][tid];
    }
  }
}

// ---------------- mixc: sage = P@xr + CPW@xl + bl, coefficients via wave-uniform s_load ----------------

__global__ __launch_bounds__(256) void mixc_kernel(
    const float* __restrict__ pc, const ushort* __restrict__ xr,
    const ushort* __restrict__ xl, const float* __restrict__ sage_bl,
    ushort* __restrict__ hbuf)
{
  int b  = blockIdx.y;
  int d0 = blockIdx.x * 256;    // grid.x = DOUT/256 = 4
  int tid = threadIdx.x;

  float xrv[S], xlv[S];
  const ushort* xrp = xr + (size_t)(b * S) * DOUT + d0 + tid;
  const ushort* xlp = xl + (size_t)(b * S) * DOUT + d0 + tid;
#pragma unroll
  for (int j = 0; j < S; ++j) {
    xrv[j] = bf2f(xrp[(size_t)j * DOUT]);
    xlv[j] = bf2f(xlp[(size_t)j * DOUT]);
  }
  float bl = sage_bl[d0 + tid];
  ushort* op = hbuf + (size_t)(b * S) * DOUT + d0 + tid;
  const float* pcb = pc + (size_t)(b * S) * 128;
  for (int i = 0; i < S; ++i) {
    const float* row = pcb + (size_t)i * 128;   // wave-uniform -> s_load path
    float acc = bl;
#pragma unroll
    for (int j = 0; j < S; ++j)
      acc += row[j] * xrv[j] + row[64 + j] * xlv[j];
    op[(size_t)i * DOUT] = f2bf(acc);
  }
}

// ---------------- fused tail ----------------

__device__ __forceinline__ float dinv_local(int j) {
  return rsqrtf((j == 0 || j == S - 1) ? 3.f : 5.f);
}

__global__ __launch_bounds__(256) void tail_fused(
    const ushort* __restrict__ gcnh, const ushort* __restrict__ Cgat,
    const ushort* __restrict__ hbuf,
    const float* __restrict__ gcn_b, const float* __restrict__ sn_g, const float* __restrict__ sn_b,
    const float* __restrict__ gat_as, const float* __restrict__ gat_ad, const float* __restrict__ gat_b,
    const float* __restrict__ mn_g, const float* __restrict__ mn_b,
    const float* __restrict__ dn_g, const float* __restrict__ dn_b,
    const float* __restrict__ gw, const float* __restrict__ gb,
    float* __restrict__ out, int N)
{
  int b  = blockIdx.x >> 2;
  int rb = blockIdx.x & 3;
  int lo = rb * 13;
  int cnt = (rb < 3) ? 13 : 2;
  size_t OUT = (size_t)N * DOUT;
  int tid = threadIdx.x;
  int wv = tid >> 6, lane = tid & 63;
  int d0 = tid * 4;
  int head = tid >> 6;

  __shared__ __align__(16) ushort hs[13][DOUT];
  __shared__ float alpha[13][13][HEADS];
  __shared__ float als_l[13][HEADS], ald_l[13][HEADS];

  for (int r = 0; r < cnt; ++r) {
    const ushort4* src = (const ushort4*)(Cgat + (size_t)(b * S + lo + r) * DOUT);
    ((ushort4*)hs[r])[tid] = src[tid];
  }
  __syncthreads();

  {
    const float4* a4 = (const float4*)(gat_as + wv * HC);
    const float4* d4 = (const float4*)(gat_ad + wv * HC);
    float4 av = a4[lane], dv = d4[lane];
    for (int s = 0; s < cnt; ++s) {
      ushort4 hv4 = ((const ushort4*)&hs[s][wv * HC])[lane];
      float h0 = bf2f(hv4.x), h1 = bf2f(hv4.y), h2 = bf2f(hv4.z), h3 = bf2f(hv4.w);
      float a = h0 * av.x + h1 * av.y + h2 * av.z + h3 * av.w;
      float d = h0 * dv.x + h1 * dv.y + h2 * dv.z + h3 * dv.w;
      a = warpReduceSum(a);
      d = warpReduceSum(d);
      if (lane == 0) { als_l[s][wv] = a; ald_l[s][wv] = d; }
    }
  }
  __syncthreads();

  if (tid < cnt * HEADS) {
    int t = tid >> 2, hd = tid & 3;
    float myald = ald_l[t][hd];
    float m = -1e30f;
    for (int s = 0; s < cnt; ++s) {
      float v = als_l[s][hd] + myald;
      v = (v > 0.f) ? v : 0.2f * v;
      m = fmaxf(m, v);
    }
    float den = 0.f;
    for (int s = 0; s < cnt; ++s) {
      float v = als_l[s][hd] + myald;
      v = (v > 0.f) ? v : 0.2f * v;
      float ev = expf(v - m) * ((s == t) ? 1.f : 2.f);  // duplicate edges -> weight 2
      alpha[t][s][hd] = ev;
      den += ev;
    }
    float inv = 1.f / den;
    for (int s = 0; s < cnt; ++s) alpha[t][s][hd] *= inv;
  }
  __syncthreads();

  float4 gcnb4 = *(const float4*)(gcn_b + d0);
  float4 sng4  = *(const float4*)(sn_g + d0);
  float4 snb4  = *(const float4*)(sn_b + d0);
  float4 gatb4 = *(const float4*)(gat_b + d0);
  float4 mng4  = *(const float4*)(mn_g + d0);
  float4 mnb4  = *(const float4*)(mn_b + d0);
  float4 dng4  = *(const float4*)(dn_g + d0);
  float4 dnb4  = *(const float4*)(dn_b + d0);
  float gwsh[4][3], gwga[4][3], gwsa[4][3];
#pragma unroll
  for (int q = 0; q < 4; ++q)
#pragma unroll
    for (int c = 0; c < 3; ++c) {
      gwsh[q][c] = gw[(size_t)(d0 + q) * 3 + c];
      gwga[q][c] = gw[(size_t)(DOUT + d0 + q) * 3 + c];
      gwsa[q][c] = gw[(size_t)(2 * DOUT + d0 + q) * 3 + c];
    }

  for (int t = 0; t < cnt; ++t) {
    int i = lo + t;
    size_t n = (size_t)(b * S + i);

    float di = dinv_local(i);
    float wc = di * di;
    float wl = (i > 0)     ? 2.f * di * dinv_local(i - 1) : 0.f;
    float wr = (i < S - 1) ? 2.f * di * dinv_local(i + 1) : 0.f;
    const ushort* hc = gcnh + n * DOUT + d0;
    ushort4 c4  = *(const ushort4*)hc;
    ushort4 lft = (i > 0)     ? *(const ushort4*)(hc - DOUT) : ushort4{0, 0, 0, 0};
    ushort4 rgt = (i < S - 1) ? *(const ushort4*)(hc + DOUT) : ushort4{0, 0, 0, 0};
    const ushort* cp = (const ushort*)&c4;
    const ushort* lp = (const ushort*)&lft;
    const ushort* rp = (const ushort*)&rgt;
    const float* gbp = (const float*)&gcnb4;
    float sh[4];
#pragma unroll
    for (int q = 0; q < 4; ++q)
      sh[q] = wc * bf2f(cp[q]) + wl * bf2f(lp[q]) + wr * bf2f(rp[q]) + gbp[q];

    float ga[4] = {0.f, 0.f, 0.f, 0.f};
    for (int si = 0; si < cnt; ++si) {
      float aj = alpha[t][si][head];
      ushort4 hv = *(const ushort4*)&hs[si][d0];
      ga[0] += aj * bf2f(hv.x);
      ga[1] += aj * bf2f(hv.y);
      ga[2] += aj * bf2f(hv.z);
      ga[3] += aj * bf2f(hv.w);
    }
    const float* gab = (const float*)&gatb4;
#pragma unroll
    for (int q = 0; q < 4; ++q) ga[q] += gab[q];

    ushort4 s4v = *(const ushort4*)(hbuf + n * DOUT + d0);
    const ushort* sp = (const ushort*)&s4v;
    float sa[4];
#pragma unroll
    for (int q = 0; q < 4; ++q) sa[q] = bf2f(sp[q]);

    float red[6] = {0.f, 0.f, 0.f, 0.f, 0.f, 0.f};
#pragma unroll
    for (int q = 0; q < 4; ++q) {
      red[0] += sh[q]; red[1] += sh[q] * sh[q];
      red[2] += ga[q]; red[3] += ga[q] * ga[q];
      red[4] += sa[q]; red[5] += sa[q] * sa[q];
    }
    blockReduce6(red);
    float mu0 = red[0] * (1.f / DOUT), r0 = rsqrtf(red[1] * (1.f / DOUT) - mu0 * mu0 + 1e-5f);
    float mu1 = red[2] * (1.f / DOUT), r1 = rsqrtf(red[3] * (1.f / DOUT) - mu1 * mu1 + 1e-5f);
    float mu2 = red[4] * (1.f / DOUT), r2 = rsqrtf(red[5] * (1.f / DOUT) - mu2 * mu2 + 1e-5f);

    const float* sngp = (const float*)&sng4; const float* snbp = (const float*)&snb4;
    const float* mngp = (const float*)&mng4; const float* mnbp = (const float*)&mnb4;
    const float* dngp = (const float*)&dng4; const float* dnbp = (const float*)&dnb4;
    float shn[4], gan[4], san[4];
#pragma unroll
    for (int q = 0; q < 4; ++q) {
      shn[q] = (sh[q] - mu0) * r0 * sngp[q] + snbp[q];
      gan[q] = (ga[q] - mu1) * r1 * mngp[q] + mnbp[q];
      san[q] = (sa[q] - mu2) * r2 * dngp[q] + dnbp[q];
    }

    float p[3] = {0.f, 0.f, 0.f};
#pragma unroll
    for (int q = 0; q < 4; ++q) {
#pragma unroll
      for (int c = 0; c < 3; ++c)
        p[c] += shn[q] * gwsh[q][c] + gan[q] * gwga[q][c] + san[q] * gwsa[q][c];
    }
    blockReduce3v(p);
    float l0 = p[0] + gb[0], l1 = p[1] + gb[1], l2 = p[2] + gb[2];
    float m = fmaxf(l0, fmaxf(l1, l2));
    float e0 = expf(l0 - m), e1 = expf(l1 - m), e2 = expf(l2 - m);
    float inv = 1.f / (e0 + e1 + e2);
    float g0 = e0 * inv, g1 = e1 * inv, g2 = e2 * inv;

    float4 o0, o1, o2;
    float* o0p = (float*)&o0; float* o1p = (float*)&o1; float* o2p = (float*)&o2;
#pragma unroll
    for (int q = 0; q < 4; ++q) {
      o0p[q] = shn[q];
      o1p[q] = gan[q];
      o2p[q] = g0 * shn[q] + g1 * gan[q] + g2 * san[q];
    }
    *(float4*)(out + n * DOUT + d0)           = o0;
    *(float4*)(out + OUT + n * DOUT + d0)     = o1;
    *(float4*)(out + 2 * OUT + n * DOUT + d0) = o2;
  }
}

// ---------------- launch ----------------

extern "C" void kernel_launch(void* const* d_in, const int* in_sizes, int n_in,
                              void* d_out, int out_size, void* d_ws, size_t ws_size,
                              hipStream_t stream) {
  const float* x       = (const float*)d_in[0];
  const float* att_w   = (const float*)d_in[1];
  const float* att_b   = (const float*)d_in[2];
  const float* gcn_w   = (const float*)d_in[3];
  const float* gcn_b   = (const float*)d_in[4];
  const float* sn_g    = (const float*)d_in[5];
  const float* sn_b    = (const float*)d_in[6];
  const float* gat_w   = (const float*)d_in[7];
  const float* gat_as  = (const float*)d_in[8];
  const float* gat_ad  = (const float*)d_in[9];
  const float* gat_b   = (const float*)d_in[10];
  const float* mn_g    = (const float*)d_in[11];
  const float* mn_b    = (const float*)d_in[12];
  const float* sage_wl = (const float*)d_in[13];
  const float* sage_bl = (const float*)d_in[14];
  const float* sage_wr = (const float*)d_in[15];
  const float* fp_w1   = (const float*)d_in[16];
  const float* fp_b1   = (const float*)d_in[17];
  const float* fp_w2   = (const float*)d_in[18];
  const float* fp_b2   = (const float*)d_in[19];
  const float* dn_g    = (const float*)d_in[20];
  const float* dn_b    = (const float*)d_in[21];
  const float* gate_w  = (const float*)d_in[22];
  const float* gate_b  = (const float*)d_in[23];

  const int B = in_sizes[0] / (S * DIN);   // 512
  const int N = B * S;                     // 20992 = 82*256
  const int MB  = N / 128;                 // 164 (fp2 GEMM)
  const int MB2 = N / 256;                 // 82  (mega GEMM)
  const int NMEGA = 4608;                  // [gcn 1024 | gat 1024 | fp1 512 | xr 1024 | xl 1024]
  float* out = (float*)d_out;

  char* ws = (char*)d_ws;
  size_t off = 0;
  auto alloc = [&](size_t bytes) { size_t p = off; off += (bytes + 255) & ~(size_t)255; return p; };
  ushort* xb   = (ushort*)(ws + alloc((size_t)N * DIN * 2));       // 53.7 MB
  ushort* Bt   = (ushort*)(ws + alloc((size_t)NMEGA * DIN * 2));   // 11.8 MB
  ushort* wpw  = (ushort*)(ws + alloc((size_t)128 * 512 * 2));     // 0.13 MB
  ushort* gcnh = (ushort*)(ws + alloc((size_t)N * DOUT * 2));      // 43 MB
  ushort* Cgat = (ushort*)(ws + alloc((size_t)N * DOUT * 2));      // 43 MB
  ushort* xr   = (ushort*)(ws + alloc((size_t)N * DOUT * 2));      // 43 MB
  ushort* xl   = (ushort*)(ws + alloc((size_t)N * DOUT * 2));      // 43 MB
  ushort* hbuf = (ushort*)(ws + alloc((size_t)N * DOUT * 2));      // 43 MB (fp1 aliases; mixc overwrites)
  float*  fp2  = (float*)(ws + alloc((size_t)N * 128 * 4));        // 10.7 MB
  float*  pc   = (float*)(ws + alloc((size_t)N * 128 * 4));        // 10.7 MB
  float*  sig  = (float*)(ws + alloc((size_t)N * 4));
  ushort* fp1  = hbuf;   // fp1 (N x 512 bf16) dead after fp2 GEMM; mixc then overwrites as hbuf

  dim3 blk(256);

  // converts + sigmoid gate
  cvtsig_kernel<<<N / 4, blk, 0, stream>>>((const float4*)x, att_w, att_b, (ushort4*)xb, sig);
  wcvt_kernel<<<dim3(DOUT / 32, DIN / 32), blk, 0, stream>>>(gcn_w, Bt, DIN, DOUT, DIN, 0);
  wcvt_kernel<<<dim3(DOUT / 32, DIN / 32), blk, 0, stream>>>(gat_w, Bt + (size_t)1024 * DIN, DIN, DOUT, DIN, 0);
  wcvt_kernel<<<dim3(512 / 32, DIN / 32), blk, 0, stream>>>(fp_w1, Bt + (size_t)2048 * DIN, DIN, 512, DIN, 0);
  wcvt_kernel<<<dim3(DOUT / 32, DIN / 32), blk, 0, stream>>>(sage_wr, Bt + (size_t)2560 * DIN, DIN, DOUT, DIN, 0);
  wcvt_kernel<<<dim3(DOUT / 32, DIN / 32), blk, 0, stream>>>(sage_wl, Bt + (size_t)3584 * DIN, DIN, DOUT, DIN, 0);
  w2cvt_kernel<<<dim3(128 * 512 / 256), blk, 0, stream>>>(fp_w2, wpw);

  // mega-GEMM (256^2 tiles): xb @ [gcn_w | gat_w | fp_w1 | sage_wr | sage_wl]
  Epi e1;
  e1.dst[0] = gcnh; e1.dst[1] = Cgat; e1.dst[2] = fp1; e1.dst[3] = xr; e1.dst[4] = xl;
  e1.bias[0] = nullptr; e1.bias[1] = nullptr; e1.bias[2] = fp_b1; e1.bias[3] = nullptr; e1.bias[4] = nullptr;
  e1.nend[0] = 1024; e1.nend[1] = 2048; e1.nend[2] = 2560; e1.nend[3] = 3584; e1.nend[4] = 4608;
  e1.ld[0] = DOUT; e1.ld[1] = DOUT; e1.ld[2] = 512; e1.ld[3] = DOUT; e1.ld[4] = DOUT;
  e1.relu[0] = 0; e1.relu[1] = 0; e1.relu[2] = 1; e1.relu[3] = 0; e1.relu[4] = 0;
  e1.rs = sig;
  gemm256<<<dim3(MB2 * (NMEGA / 256)), dim3(512), 0, stream>>>(xb, Bt, DIN, NMEGA / 256, e1);

  // fp2 logits GEMM (N=128 padded) — 128^2 kernel
  Epi epw;
  epw.dst[0] = fp2; epw.dst[1] = nullptr; epw.dst[2] = nullptr; epw.dst[3] = nullptr; epw.dst[4] = nullptr;
  epw.bias[0] = nullptr; epw.bias[1] = nullptr; epw.bias[2] = nullptr; epw.bias[3] = nullptr; epw.bias[4] = nullptr;
  epw.nend[0] = 1 << 30; epw.nend[1] = 1 << 30; epw.nend[2] = 1 << 30; epw.nend[3] = 1 << 30; epw.nend[4] = 1 << 30;
  epw.ld[0] = 128; epw.ld[1] = 128; epw.ld[2] = 128; epw.ld[3] = 128; epw.ld[4] = 128;
  epw.relu[0] = 0; epw.relu[1] = 0; epw.relu[2] = 0; epw.relu[3] = 0; epw.relu[4] = 0;
  epw.rs = nullptr;
  gemm_bf16<true><<<dim3(MB), blk, 0, stream>>>(fp1, wpw, 512, 1, epw);

  // deep combine: softmax+prefix coefficients -> pc (global), then s_load-driven mixing
  pwprep_kernel<<<B, blk, 0, stream>>>(fp2, fp_b2, pc);
  mixc_kernel<<<dim3(DOUT / 256, B), blk, 0, stream>>>(pc, xr, xl, sage_bl, hbuf);

  // fused tail: all three branches + gate -> out0/out1/out2
  tail_fused<<<B * 4, blk, 0, stream>>>(gcnh, Cgat, hbuf,
                                        gcn_b, sn_g, sn_b,
                                        gat_as, gat_ad, gat_b,
                                        mn_g, mn_b, dn_g, dn_b,
                                        gate_w, gate_b, out, N);
}

// Round 12
// 693.201 us; speedup vs baseline: 1.0108x; 1.0108x over previous
//
#include <hip/hip_runtime.h>
#include <math.h>

static constexpr int S    = 41;
static constexpr int DIN  = 1280;
static constexpr int DOUT = 1024;
static constexpr int HEADS = 4;
static constexpr int HC   = 256;

typedef __attribute__((ext_vector_type(4))) float f32x4;
typedef __attribute__((ext_vector_type(8))) short short8;

__device__ __forceinline__ ushort f2bf(float f) {
  uint u = __float_as_uint(f);
  uint r = u + 0x7fffu + ((u >> 16) & 1u);   // RNE
  return (ushort)(r >> 16);
}
__device__ __forceinline__ float bf2f(ushort u) {
  return __uint_as_float(((uint)u) << 16);
}

__device__ __forceinline__ void gload16(const ushort* g, ushort* l) {
  __builtin_amdgcn_global_load_lds((const __attribute__((address_space(1))) void*)g,
                                   (__attribute__((address_space(3))) void*)l, 16, 0, 0);
}

// ---------------- reduction helpers ----------------

__device__ __forceinline__ float warpReduceSum(float v) {
#pragma unroll
  for (int off = 32; off; off >>= 1) v += __shfl_down(v, off);
  return v;
}

__device__ __forceinline__ void blockReduce6(float* v) {
  __shared__ float red6[6][4];
  int w = threadIdx.x >> 6, lane = threadIdx.x & 63;
#pragma unroll
  for (int r = 0; r < 6; ++r) v[r] = warpReduceSum(v[r]);
  __syncthreads();
  if (lane == 0) {
#pragma unroll
    for (int r = 0; r < 6; ++r) red6[r][w] = v[r];
  }
  __syncthreads();
#pragma unroll
  for (int r = 0; r < 6; ++r)
    v[r] = red6[r][0] + red6[r][1] + red6[r][2] + red6[r][3];
}

__device__ __forceinline__ void blockReduce3v(float* v) {
  __shared__ float red3[3][4];
  int w = threadIdx.x >> 6, lane = threadIdx.x & 63;
#pragma unroll
  for (int r = 0; r < 3; ++r) v[r] = warpReduceSum(v[r]);
  __syncthreads();
  if (lane == 0) {
#pragma unroll
    for (int r = 0; r < 3; ++r) red3[r][w] = v[r];
  }
  __syncthreads();
#pragma unroll
  for (int r = 0; r < 3; ++r)
    v[r] = red3[r][0] + red3[r][1] + red3[r][2] + red3[r][3];
}

// ---------------- fused x->bf16 convert + sigmoid row gate ----------------

__global__ __launch_bounds__(256) void cvtsig_kernel(
    const float4* __restrict__ x, const float* __restrict__ att_w,
    const float* __restrict__ att_b, ushort4* __restrict__ xb, float* __restrict__ sig)
{
  int row  = blockIdx.x * 4 + (threadIdx.x >> 6);
  int lane = threadIdx.x & 63;
  const float4* xr = x + (size_t)row * (DIN / 4);
  const float4* wr = (const float4*)att_w;
  ushort4* xo = xb + (size_t)row * (DIN / 4);
  float acc = 0.f;
#pragma unroll
  for (int k = 0; k < DIN / 4 / 64; ++k) {   // 5
    float4 a = xr[lane + k * 64];
    float4 w = wr[lane + k * 64];
    acc += a.x * w.x + a.y * w.y + a.z * w.z + a.w * w.w;
    ushort4 o;
    o.x = f2bf(a.x); o.y = f2bf(a.y); o.z = f2bf(a.z); o.w = f2bf(a.w);
    xo[lane + k * 64] = o;
  }
  acc = warpReduceSum(acc);
  if (lane == 0) sig[row] = 1.f / (1.f + expf(-(acc + att_b[0])));
}

// ---------------- weight converts ----------------

__global__ __launch_bounds__(256) void wcvt_kernel(const float* __restrict__ W,
                                                   ushort* __restrict__ out,
                                                   int K, int N, int ostride, int koff) {
  __shared__ float t[32][33];
  int n0 = blockIdx.x * 32, k0 = blockIdx.y * 32;
  int tx = threadIdx.x & 31, ty = threadIdx.x >> 5;
#pragma unroll
  for (int r = 0; r < 4; ++r) {
    int k = ty + r * 8;
    t[k][tx] = W[(size_t)(k0 + k) * N + n0 + tx];
  }
  __syncthreads();
#pragma unroll
  for (int r = 0; r < 4; ++r) {
    int nn = ty + r * 8;
    out[(size_t)(n0 + nn) * ostride + koff + k0 + tx] = f2bf(t[tx][nn]);
  }
}

// wpw[n][k] = n<41 ? bf16(w2[k][n]) : 0   (128 x 512)
__global__ __launch_bounds__(256) void w2cvt_kernel(const float* __restrict__ w2,
                                                    ushort* __restrict__ wpw) {
  int idx = blockIdx.x * 256 + threadIdx.x;
  int n = idx >> 9, k = idx & 511;
  wpw[idx] = (n < S) ? f2bf(w2[(size_t)k * S + n]) : (ushort)0;
}

// ---------------- shared epilogue descriptor ----------------

struct Epi {
  void* dst[5];
  const float* bias[5];
  int nend[5];
  int ld[5];
  int relu[5];
  const float* rs;             // rowscale, branch 0 only
};

// ---------------- 8-phase 256^2 bf16 MFMA GEMM (T3+T4 schedule) ----------------
// BK=64, 8 waves (2M x 4N), per-wave output 128x64. LDS = 2 dbuf x 2 K-half x
// [256][32] per operand = 128 KB. Per phase: stage 1 half-unit (2 gloads/thr)
// + ds_read subtile + barrier + 16 MFMA. vmcnt(8) counted at P0/P2 (4 units x
// 2 loads in flight); tail vmcnt(4)/(0) at last tile. Chunk-rotation swizzle
// (rule #21): source chunk = (pos - ((row>>1)&3))&3; read chunk = (l4+rot)&3.

__global__ __launch_bounds__(512, 1) void gemm8p(
    const ushort* __restrict__ A, const ushort* __restrict__ Bt, int K, int nb, Epi e)
{
  __shared__ __align__(16) ushort As[4 * 8192];   // [db*2+ks][256][32] : 64 KB
  __shared__ __align__(16) ushort Bs[4 * 8192];   // 64 KB

  const int bid = blockIdx.x;
  const int bm  = (bid / nb) * 256;   // bn-fastest: consecutive blocks share A panel
  const int bn  = (bid % nb) * 256;

  const int tid  = threadIdx.x;
  const int wv   = tid >> 6;          // 0..7
  const int lane = tid & 63;
  const int l16  = lane & 15;
  const int l4   = lane >> 4;
  const int m0   = (wv >> 2) * 128;   // 2 M-strips
  const int n0   = (wv & 3) * 64;     // 4 N-strips

  // stage addressing: gload g covers rows [g*128, g*128+128) of the unit
  const int rd0 = wv * 16 + (lane >> 2);         // g=0 row
  const int rd1 = 128 + wv * 16 + (lane >> 2);   // g=1 row
  const int cs0 = ((lane & 3) - ((rd0 >> 1) & 3)) & 3;   // inverse-permuted src chunk
  const int cs1 = ((lane & 3) - ((rd1 >> 1) & 3)) & 3;

  auto stageA = [&](int h, int Tt) {     // h = db*2+ks
    int kof = Tt * 64 + (h & 1) * 32;
    gload16(A + (size_t)(bm + rd0) * K + kof + cs0 * 8, &As[h * 8192 + wv * 512]);
    gload16(A + (size_t)(bm + rd1) * K + kof + cs1 * 8, &As[h * 8192 + (8 + wv) * 512]);
  };
  auto stageB = [&](int h, int Tt) {
    int kof = Tt * 64 + (h & 1) * 32;
    gload16(Bt + (size_t)(bn + rd0) * K + kof + cs0 * 8, &Bs[h * 8192 + wv * 512]);
    gload16(Bt + (size_t)(bn + rd1) * K + kof + cs1 * 8, &Bs[h * 8192 + (8 + wv) * 512]);
  };

  // read-side rotation: rot(r) = (r>>1)&3 reduces to (l16>>1)&3 (m0,n0,i*16 are 0 mod 8 after >>1&3)
  const int rchunk = ((l4 + ((l16 >> 1) & 3)) & 3) * 8;

  f32x4 acc[8][4];
#pragma unroll
  for (int i = 0; i < 8; ++i)
#pragma unroll
    for (int j = 0; j < 4; ++j) acc[i][j] = (f32x4)0.f;

  const int NT = K >> 6;   // 64-K tiles (>=2)

  // prologue: tile0 full + tile1 ks0  (6 units = 12 loads/thread)
  stageA(0, 0); stageB(0, 0);      // db0 ks0
  stageA(1, 0); stageB(1, 0);      // db0 ks1
  stageA(2, 1); stageB(2, 1);      // db1 ks0

  for (int T = 0; T < NT; ++T) {
    const int db = T & 1;
    const int hA = db * 2;          // ks0 half of current buffer
    const int hB = db * 2 + 1;      // ks1 half
    short8 a[4], b[4];

    // ---- P0: needs ks0(T); stage A-ks1(T+1); MFMA i0-3 x ks0 ----
    if (T + 1 < NT) asm volatile("s_waitcnt vmcnt(8)" ::: "memory");
    else            asm volatile("s_waitcnt vmcnt(4)" ::: "memory");
    __builtin_amdgcn_s_barrier();
    asm volatile("" ::: "memory");
    if (T + 1 < NT) stageA((db ^ 1) * 2 + 1, T + 1);
#pragma unroll
    for (int i = 0; i < 4; ++i)
      a[i] = *reinterpret_cast<const short8*>(&As[hA * 8192 + (m0 + i * 16 + l16) * 32 + rchunk]);
#pragma unroll
    for (int j = 0; j < 4; ++j)
      b[j] = *reinterpret_cast<const short8*>(&Bs[hA * 8192 + (n0 + j * 16 + l16) * 32 + rchunk]);
    __builtin_amdgcn_s_setprio(1);
#pragma unroll
    for (int i = 0; i < 4; ++i)
#pragma unroll
      for (int j = 0; j < 4; ++j)
        acc[i][j] = __builtin_amdgcn_mfma_f32_16x16x32_bf16(a[i], b[j], acc[i][j], 0, 0, 0);
    __builtin_amdgcn_s_setprio(0);

    // ---- P1: stage B-ks1(T+1); MFMA i4-7 x ks0 ----
    __builtin_amdgcn_s_barrier();
    asm volatile("" ::: "memory");
    if (T + 1 < NT) stageB((db ^ 1) * 2 + 1, T + 1);
#pragma unroll
    for (int i = 0; i < 4; ++i)
      a[i] = *reinterpret_cast<const short8*>(&As[hA * 8192 + (m0 + 64 + i * 16 + l16) * 32 + rchunk]);
    __builtin_amdgcn_s_setprio(1);
#pragma unroll
    for (int i = 0; i < 4; ++i)
#pragma unroll
      for (int j = 0; j < 4; ++j)
        acc[4 + i][j] = __builtin_amdgcn_mfma_f32_16x16x32_bf16(a[i], b[j], acc[4 + i][j], 0, 0, 0);
    __builtin_amdgcn_s_setprio(0);

    // ---- P2: needs ks1(T); stage A-ks0(T+2) into freed half; MFMA i0-3 x ks1 ----
    if (T + 1 < NT) asm volatile("s_waitcnt vmcnt(8)" ::: "memory");
    else            asm volatile("s_waitcnt vmcnt(0)" ::: "memory");
    __builtin_amdgcn_s_barrier();
    asm volatile("" ::: "memory");
    if (T + 2 < NT) stageA(db * 2, T + 2);
#pragma unroll
    for (int i = 0; i < 4; ++i)
      a[i] = *reinterpret_cast<const short8*>(&As[hB * 8192 + (m0 + i * 16 + l16) * 32 + rchunk]);
#pragma unroll
    for (int j = 0; j < 4; ++j)
      b[j] = *reinterpret_cast<const short8*>(&Bs[hB * 8192 + (n0 + j * 16 + l16) * 32 + rchunk]);
    __builtin_amdgcn_s_setprio(1);
#pragma unroll
    for (int i = 0; i < 4; ++i)
#pragma unroll
      for (int j = 0; j < 4; ++j)
        acc[i][j] = __builtin_amdgcn_mfma_f32_16x16x32_bf16(a[i], b[j], acc[i][j], 0, 0, 0);
    __builtin_amdgcn_s_setprio(0);

    // ---- P3: stage B-ks0(T+2); MFMA i4-7 x ks1 ----
    __builtin_amdgcn_s_barrier();
    asm volatile("" ::: "memory");
    if (T + 2 < NT) stageB(db * 2, T + 2);
#pragma unroll
    for (int i = 0; i < 4; ++i)
      a[i] = *reinterpret_cast<const short8*>(&As[hB * 8192 + (m0 + 64 + i * 16 + l16) * 32 + rchunk]);
    __builtin_amdgcn_s_setprio(1);
#pragma unroll
    for (int i = 0; i < 4; ++i)
#pragma unroll
      for (int j = 0; j < 4; ++j)
        acc[4 + i][j] = __builtin_amdgcn_mfma_f32_16x16x32_bf16(a[i], b[j], acc[4 + i][j], 0, 0, 0);
    __builtin_amdgcn_s_setprio(0);
  }

  void* dstv; const float* bias; const float* rs = nullptr; int ldc, cb, relu;
  if (bn < e.nend[0])      { dstv = e.dst[0]; ldc = e.ld[0]; cb = bn;             bias = e.bias[0]; relu = e.relu[0]; rs = e.rs; }
  else if (bn < e.nend[1]) { dstv = e.dst[1]; ldc = e.ld[1]; cb = bn - e.nend[0]; bias = e.bias[1]; relu = e.relu[1]; }
  else if (bn < e.nend[2]) { dstv = e.dst[2]; ldc = e.ld[2]; cb = bn - e.nend[1]; bias = e.bias[2]; relu = e.relu[2]; }
  else if (bn < e.nend[3]) { dstv = e.dst[3]; ldc = e.ld[3]; cb = bn - e.nend[2]; bias = e.bias[3]; relu = e.relu[3]; }
  else                     { dstv = e.dst[4]; ldc = e.ld[4]; cb = bn - e.nend[3]; bias = e.bias[4]; relu = e.relu[4]; }

#pragma unroll
  for (int i = 0; i < 8; ++i) {
    int mbase = bm + m0 + i * 16 + l4 * 4;
    float rsv[4];
#pragma unroll
    for (int r = 0; r < 4; ++r) rsv[r] = rs ? rs[mbase + r] : 1.f;
#pragma unroll
    for (int j = 0; j < 4; ++j) {
      int col = cb + n0 + j * 16 + l16;
      float bv = bias ? bias[col] : 0.f;
#pragma unroll
      for (int r = 0; r < 4; ++r) {
        float t = acc[i][j][r] * rsv[r] + bv;
        if (relu) t = fmaxf(t, 0.f);
        ((ushort*)dstv)[(size_t)(mbase + r) * ldc + col] = f2bf(t);
      }
    }
  }
}

// ---------------- 128x128 bf16 MFMA GEMM (fp2 GEMM; r10-verified ring) ----------------

template<bool F32OUT>
__global__ __launch_bounds__(256) void gemm_bf16(
    const ushort* __restrict__ A, const ushort* __restrict__ Bt, int K, int nb, Epi e)
{
  __shared__ __align__(16) ushort As[3][128 * 32];
  __shared__ __align__(16) ushort Bs[3][128 * 32];

  const int bid = blockIdx.x;
  const int bm  = (bid / nb) * 128;
  const int bn  = (bid % nb) * 128;

  const int tid  = threadIdx.x;
  const int w    = tid >> 6;
  const int lane = tid & 63;
  const int l16  = lane & 15;
  const int l4   = lane >> 4;
  const int m0   = (w >> 1) * 64;
  const int n0   = (w & 1) * 64;

  const int rloc = lane >> 2;
  const int cpos = lane & 3;
  const int cdat = (cpos - (rloc >> 1)) & 3;
  const int srow = w * 32 + rloc;
  const int scol = cdat * 8;

  f32x4 acc[4][4];
#pragma unroll
  for (int i = 0; i < 4; ++i)
#pragma unroll
    for (int j = 0; j < 4; ++j) acc[i][j] = (f32x4)0.f;

  const ushort* pA0 = A  + (size_t)(bm + srow) * K + scol;
  const ushort* pA1 = A  + (size_t)(bm + srow + 16) * K + scol;
  const ushort* pB0 = Bt + (size_t)(bn + srow) * K + scol;
  const ushort* pB1 = Bt + (size_t)(bn + srow + 16) * K + scol;

  auto stage = [&](int buf, int kt) {
    gload16(pA0 + kt, &As[buf][w * 1024]);
    gload16(pA1 + kt, &As[buf][w * 1024 + 512]);
    gload16(pB0 + kt, &Bs[buf][w * 1024]);
    gload16(pB1 + kt, &Bs[buf][w * 1024 + 512]);
  };

  const int rchunk = ((l4 + (l16 >> 1)) & 3) * 8;

  const int nsteps = K >> 5;
  stage(0, 0); stage(1, 32); stage(2, 64);

  for (int t = 0; t < nsteps; ++t) {
    if (t == 0)                asm volatile("s_waitcnt vmcnt(8)" ::: "memory");
    else if (t == nsteps - 1)  asm volatile("s_waitcnt vmcnt(0)" ::: "memory");
    else                       asm volatile("s_waitcnt vmcnt(4)" ::: "memory");
    __builtin_amdgcn_s_barrier();
    asm volatile("" ::: "memory");

    if (t >= 1 && t + 2 < nsteps) stage((t + 2) % 3, (t + 2) * 32);

    const int cur = t % 3;
    short8 a[4], b[4];
#pragma unroll
    for (int i = 0; i < 4; ++i)
      a[i] = *reinterpret_cast<const short8*>(&As[cur][(m0 + i * 16 + l16) * 32 + rchunk]);
#pragma unroll
    for (int j = 0; j < 4; ++j)
      b[j] = *reinterpret_cast<const short8*>(&Bs[cur][(n0 + j * 16 + l16) * 32 + rchunk]);
    __builtin_amdgcn_s_setprio(1);
#pragma unroll
    for (int i = 0; i < 4; ++i)
#pragma unroll
      for (int j = 0; j < 4; ++j)
        acc[i][j] = __builtin_amdgcn_mfma_f32_16x16x32_bf16(a[i], b[j], acc[i][j], 0, 0, 0);
    __builtin_amdgcn_s_setprio(0);
  }

  void* dstv; const float* bias; const float* rs = nullptr; int ldc, cb, relu;
  if (bn < e.nend[0])      { dstv = e.dst[0]; ldc = e.ld[0]; cb = bn;             bias = e.bias[0]; relu = e.relu[0]; rs = e.rs; }
  else if (bn < e.nend[1]) { dstv = e.dst[1]; ldc = e.ld[1]; cb = bn - e.nend[0]; bias = e.bias[1]; relu = e.relu[1]; }
  else if (bn < e.nend[2]) { dstv = e.dst[2]; ldc = e.ld[2]; cb = bn - e.nend[1]; bias = e.bias[2]; relu = e.relu[2]; }
  else if (bn < e.nend[3]) { dstv = e.dst[3]; ldc = e.ld[3]; cb = bn - e.nend[2]; bias = e.bias[3]; relu = e.relu[3]; }
  else                     { dstv = e.dst[4]; ldc = e.ld[4]; cb = bn - e.nend[3]; bias = e.bias[4]; relu = e.relu[4]; }

#pragma unroll
  for (int i = 0; i < 4; ++i) {
    int mbase = bm + m0 + i * 16 + l4 * 4;
    float rsv[4];
#pragma unroll
    for (int r = 0; r < 4; ++r) rsv[r] = rs ? rs[mbase + r] : 1.f;
#pragma unroll
    for (int j = 0; j < 4; ++j) {
      int col = cb + n0 + j * 16 + l16;
      float bv = bias ? bias[col] : 0.f;
#pragma unroll
      for (int r = 0; r < 4; ++r) {
        float t = acc[i][j][r] * rsv[r] + bv;
        if (relu) t = fmaxf(t, 0.f);
        if (F32OUT) ((float*)dstv)[(size_t)(mbase + r) * ldc + col] = t;
        else        ((ushort*)dstv)[(size_t)(mbase + r) * ldc + col] = f2bf(t);
      }
    }
  }
}

// ---------------- pwprep: softmax rows + prefix-mean rows -> global pc (f32) ----------------

__global__ __launch_bounds__(256) void pwprep_kernel(
    const float* __restrict__ fp2, const float* __restrict__ fp_b2,
    float* __restrict__ pc)
{
  int b = blockIdx.x;
  int tid = threadIdx.x, wv = tid >> 6, lane = tid & 63;
  __shared__ float pws[S][S];
  for (int i = wv; i < S; i += 4) {
    float v = (lane < S) ? (fp2[(size_t)(b * S + i) * 128 + lane] + fp_b2[lane]) : -1e30f;
    float m = v;
#pragma unroll
    for (int off = 32; off; off >>= 1) m = fmaxf(m, __shfl_xor(m, off));
    float e = (lane < S) ? expf(v - m) : 0.f;
    float sum = e;
#pragma unroll
    for (int off = 32; off; off >>= 1) sum += __shfl_xor(sum, off);
    if (lane < S) {
      float p = e / sum;
      pws[i][lane] = p;
      pc[((size_t)b * S + i) * 128 + lane] = p;
    }
  }
  __syncthreads();
  if (tid < S) {
    float run = 0.f;
    for (int i = 0; i < S; ++i) {
      pc[((size_t)b * S + i) * 128 + 64 + tid] = (i > 0) ? run / (float)i : 0.f;
      run += pws[i][tid];
    }
  }
}

// ---------------- mixc: sage = P@xr + CPW@xl + bl, coefficients via wave-uniform s_load ----------------

__global__ __launch_bounds__(256) void mixc_kernel(
    const float* __restrict__ pc, const ushort* __restrict__ xr,
    const ushort* __restrict__ xl, const float* __restrict__ sage_bl,
    ushort* __restrict__ hbuf)
{
  int b  = blockIdx.y;
  int d0 = blockIdx.x * 256;    // grid.x = DOUT/256 = 4
  int tid = threadIdx.x;

  float xrv[S], xlv[S];
  const ushort* xrp = xr + (size_t)(b * S) * DOUT + d0 + tid;
  const ushort* xlp = xl + (size_t)(b * S) * DOUT + d0 + tid;
#pragma unroll
  for (int j = 0; j < S; ++j) {
    xrv[j] = bf2f(xrp[(size_t)j * DOUT]);
    xlv[j] = bf2f(xlp[(size_t)j * DOUT]);
  }
  float bl = sage_bl[d0 + tid];
  ushort* op = hbuf + (size_t)(b * S) * DOUT + d0 + tid;
  const float* pcb = pc + (size_t)(b * S) * 128;
  for (int i = 0; i < S; ++i) {
    const float* row = pcb + (size_t)i * 128;   // wave-uniform -> s_load path
    float acc = bl;
#pragma unroll
    for (int j = 0; j < S; ++j)
      acc += row[j] * xrv[j] + row[64 + j] * xlv[j];
    op[(size_t)i * DOUT] = f2bf(acc);
  }
}

// ---------------- fused tail ----------------

__device__ __forceinline__ float dinv_local(int j) {
  return rsqrtf((j == 0 || j == S - 1) ? 3.f : 5.f);
}

__global__ __launch_bounds__(256) void tail_fused(
    const ushort* __restrict__ gcnh, const ushort* __restrict__ Cgat,
    const ushort* __restrict__ hbuf,
    const float* __restrict__ gcn_b, const float* __restrict__ sn_g, const float* __restrict__ sn_b,
    const float* __restrict__ gat_as, const float* __restrict__ gat_ad, const float* __restrict__ gat_b,
    const float* __restrict__ mn_g, const float* __restrict__ mn_b,
    const float* __restrict__ dn_g, const float* __restrict__ dn_b,
    const float* __restrict__ gw, const float* __restrict__ gb,
    float* __restrict__ out, int N)
{
  int b  = blockIdx.x >> 2;
  int rb = blockIdx.x & 3;
  int lo = rb * 13;
  int cnt = (rb < 3) ? 13 : 2;
  size_t OUT = (size_t)N * DOUT;
  int tid = threadIdx.x;
  int wv = tid >> 6, lane = tid & 63;
  int d0 = tid * 4;
  int head = tid >> 6;

  __shared__ __align__(16) ushort hs[13][DOUT];
  __shared__ float alpha[13][13][HEADS];
  __shared__ float als_l[13][HEADS], ald_l[13][HEADS];

  for (int r = 0; r < cnt; ++r) {
    const ushort4* src = (const ushort4*)(Cgat + (size_t)(b * S + lo + r) * DOUT);
    ((ushort4*)hs[r])[tid] = src[tid];
  }
  __syncthreads();

  {
    const float4* a4 = (const float4*)(gat_as + wv * HC);
    const float4* d4 = (const float4*)(gat_ad + wv * HC);
    float4 av = a4[lane], dv = d4[lane];
    for (int s = 0; s < cnt; ++s) {
      ushort4 hv4 = ((const ushort4*)&hs[s][wv * HC])[lane];
      float h0 = bf2f(hv4.x), h1 = bf2f(hv4.y), h2 = bf2f(hv4.z), h3 = bf2f(hv4.w);
      float a = h0 * av.x + h1 * av.y + h2 * av.z + h3 * av.w;
      float d = h0 * dv.x + h1 * dv.y + h2 * dv.z + h3 * dv.w;
      a = warpReduceSum(a);
      d = warpReduceSum(d);
      if (lane == 0) { als_l[s][wv] = a; ald_l[s][wv] = d; }
    }
  }
  __syncthreads();

  if (tid < cnt * HEADS) {
    int t = tid >> 2, hd = tid & 3;
    float myald = ald_l[t][hd];
    float m = -1e30f;
    for (int s = 0; s < cnt; ++s) {
      float v = als_l[s][hd] + myald;
      v = (v > 0.f) ? v : 0.2f * v;
      m = fmaxf(m, v);
    }
    float den = 0.f;
    for (int s = 0; s < cnt; ++s) {
      float v = als_l[s][hd] + myald;
      v = (v > 0.f) ? v : 0.2f * v;
      float ev = expf(v - m) * ((s == t) ? 1.f : 2.f);  // duplicate edges -> weight 2
      alpha[t][s][hd] = ev;
      den += ev;
    }
    float inv = 1.f / den;
    for (int s = 0; s < cnt; ++s) alpha[t][s][hd] *= inv;
  }
  __syncthreads();

  float4 gcnb4 = *(const float4*)(gcn_b + d0);
  float4 sng4  = *(const float4*)(sn_g + d0);
  float4 snb4  = *(const float4*)(sn_b + d0);
  float4 gatb4 = *(const float4*)(gat_b + d0);
  float4 mng4  = *(const float4*)(mn_g + d0);
  float4 mnb4  = *(const float4*)(mn_b + d0);
  float4 dng4  = *(const float4*)(dn_g + d0);
  float4 dnb4  = *(const float4*)(dn_b + d0);
  float gwsh[4][3], gwga[4][3], gwsa[4][3];
#pragma unroll
  for (int q = 0; q < 4; ++q)
#pragma unroll
    for (int c = 0; c < 3; ++c) {
      gwsh[q][c] = gw[(size_t)(d0 + q) * 3 + c];
      gwga[q][c] = gw[(size_t)(DOUT + d0 + q) * 3 + c];
      gwsa[q][c] = gw[(size_t)(2 * DOUT + d0 + q) * 3 + c];
    }

  for (int t = 0; t < cnt; ++t) {
    int i = lo + t;
    size_t n = (size_t)(b * S + i);

    float di = dinv_local(i);
    float wc = di * di;
    float wl = (i > 0)     ? 2.f * di * dinv_local(i - 1) : 0.f;
    float wr = (i < S - 1) ? 2.f * di * dinv_local(i + 1) : 0.f;
    const ushort* hc = gcnh + n * DOUT + d0;
    ushort4 c4  = *(const ushort4*)hc;
    ushort4 lft = (i > 0)     ? *(const ushort4*)(hc - DOUT) : ushort4{0, 0, 0, 0};
    ushort4 rgt = (i < S - 1) ? *(const ushort4*)(hc + DOUT) : ushort4{0, 0, 0, 0};
    const ushort* cp = (const ushort*)&c4;
    const ushort* lp = (const ushort*)&lft;
    const ushort* rp = (const ushort*)&rgt;
    const float* gbp = (const float*)&gcnb4;
    float sh[4];
#pragma unroll
    for (int q = 0; q < 4; ++q)
      sh[q] = wc * bf2f(cp[q]) + wl * bf2f(lp[q]) + wr * bf2f(rp[q]) + gbp[q];

    float ga[4] = {0.f, 0.f, 0.f, 0.f};
    for (int si = 0; si < cnt; ++si) {
      float aj = alpha[t][si][head];
      ushort4 hv = *(const ushort4*)&hs[si][d0];
      ga[0] += aj * bf2f(hv.x);
      ga[1] += aj * bf2f(hv.y);
      ga[2] += aj * bf2f(hv.z);
      ga[3] += aj * bf2f(hv.w);
    }
    const float* gab = (const float*)&gatb4;
#pragma unroll
    for (int q = 0; q < 4; ++q) ga[q] += gab[q];

    ushort4 s4v = *(const ushort4*)(hbuf + n * DOUT + d0);
    const ushort* sp = (const ushort*)&s4v;
    float sa[4];
#pragma unroll
    for (int q = 0; q < 4; ++q) sa[q] = bf2f(sp[q]);

    float red[6] = {0.f, 0.f, 0.f, 0.f, 0.f, 0.f};
#pragma unroll
    for (int q = 0; q < 4; ++q) {
      red[0] += sh[q]; red[1] += sh[q] * sh[q];
      red[2] += ga[q]; red[3] += ga[q] * ga[q];
      red[4] += sa[q]; red[5] += sa[q] * sa[q];
    }
    blockReduce6(red);
    float mu0 = red[0] * (1.f / DOUT), r0 = rsqrtf(red[1] * (1.f / DOUT) - mu0 * mu0 + 1e-5f);
    float mu1 = red[2] * (1.f / DOUT), r1 = rsqrtf(red[3] * (1.f / DOUT) - mu1 * mu1 + 1e-5f);
    float mu2 = red[4] * (1.f / DOUT), r2 = rsqrtf(red[5] * (1.f / DOUT) - mu2 * mu2 + 1e-5f);

    const float* sngp = (const float*)&sng4; const float* snbp = (const float*)&snb4;
    const float* mngp = (const float*)&mng4; const float* mnbp = (const float*)&mnb4;
    const float* dngp = (const float*)&dng4; const float* dnbp = (const float*)&dnb4;
    float shn[4], gan[4], san[4];
#pragma unroll
    for (int q = 0; q < 4; ++q) {
      shn[q] = (sh[q] - mu0) * r0 * sngp[q] + snbp[q];
      gan[q] = (ga[q] - mu1) * r1 * mngp[q] + mnbp[q];
      san[q] = (sa[q] - mu2) * r2 * dngp[q] + dnbp[q];
    }

    float p[3] = {0.f, 0.f, 0.f};
#pragma unroll
    for (int q = 0; q < 4; ++q) {
#pragma unroll
      for (int c = 0; c < 3; ++c)
        p[c] += shn[q] * gwsh[q][c] + gan[q] * gwga[q][c] + san[q] * gwsa[q][c];
    }
    blockReduce3v(p);
    float l0 = p[0] + gb[0], l1 = p[1] + gb[1], l2 = p[2] + gb[2];
    float m = fmaxf(l0, fmaxf(l1, l2));
    float e0 = expf(l0 - m), e1 = expf(l1 - m), e2 = expf(l2 - m);
    float inv = 1.f / (e0 + e1 + e2);
    float g0 = e0 * inv, g1 = e1 * inv, g2 = e2 * inv;

    float4 o0, o1, o2;
    float* o0p = (float*)&o0; float* o1p = (float*)&o1; float* o2p = (float*)&o2;
#pragma unroll
    for (int q = 0; q < 4; ++q) {
      o0p[q] = shn[q];
      o1p[q] = gan[q];
      o2p[q] = g0 * shn[q] + g1 * gan[q] + g2 * san[q];
    }
    *(float4*)(out + n * DOUT + d0)           = o0;
    *(float4*)(out + OUT + n * DOUT + d0)     = o1;
    *(float4*)(out + 2 * OUT + n * DOUT + d0) = o2;
  }
}

// ---------------- launch ----------------

extern "C" void kernel_launch(void* const* d_in, const int* in_sizes, int n_in,
                              void* d_out, int out_size, void* d_ws, size_t ws_size,
                              hipStream_t stream) {
  const float* x       = (const float*)d_in[0];
  const float* att_w   = (const float*)d_in[1];
  const float* att_b   = (const float*)d_in[2];
  const float* gcn_w   = (const float*)d_in[3];
  const float* gcn_b   = (const float*)d_in[4];
  const float* sn_g    = (const float*)d_in[5];
  const float* sn_b    = (const float*)d_in[6];
  const float* gat_w   = (const float*)d_in[7];
  const float* gat_as  = (const float*)d_in[8];
  const float* gat_ad  = (const float*)d_in[9];
  const float* gat_b   = (const float*)d_in[10];
  const float* mn_g    = (const float*)d_in[11];
  const float* mn_b    = (const float*)d_in[12];
  const float* sage_wl = (const float*)d_in[13];
  const float* sage_bl = (const float*)d_in[14];
  const float* sage_wr = (const float*)d_in[15];
  const float* fp_w1   = (const float*)d_in[16];
  const float* fp_b1   = (const float*)d_in[17];
  const float* fp_w2   = (const float*)d_in[18];
  const float* fp_b2   = (const float*)d_in[19];
  const float* dn_g    = (const float*)d_in[20];
  const float* dn_b    = (const float*)d_in[21];
  const float* gate_w  = (const float*)d_in[22];
  const float* gate_b  = (const float*)d_in[23];

  const int B = in_sizes[0] / (S * DIN);   // 512
  const int N = B * S;                     // 20992 = 82*256
  const int MB  = N / 128;                 // 164 (fp2 GEMM)
  const int MB2 = N / 256;                 // 82  (mega GEMM)
  const int NMEGA = 4608;                  // [gcn 1024 | gat 1024 | fp1 512 | xr 1024 | xl 1024]
  float* out = (float*)d_out;

  char* ws = (char*)d_ws;
  size_t off = 0;
  auto alloc = [&](size_t bytes) { size_t p = off; off += (bytes + 255) & ~(size_t)255; return p; };
  ushort* xb   = (ushort*)(ws + alloc((size_t)N * DIN * 2));       // 53.7 MB
  ushort* Bt   = (ushort*)(ws + alloc((size_t)NMEGA * DIN * 2));   // 11.8 MB
  ushort* wpw  = (ushort*)(ws + alloc((size_t)128 * 512 * 2));     // 0.13 MB
  ushort* gcnh = (ushort*)(ws + alloc((size_t)N * DOUT * 2));      // 43 MB
  ushort* Cgat = (ushort*)(ws + alloc((size_t)N * DOUT * 2));      // 43 MB
  ushort* xr   = (ushort*)(ws + alloc((size_t)N * DOUT * 2));      // 43 MB
  ushort* xl   = (ushort*)(ws + alloc((size_t)N * DOUT * 2));      // 43 MB
  ushort* hbuf = (ushort*)(ws + alloc((size_t)N * DOUT * 2));      // 43 MB (fp1 aliases; mixc overwrites)
  float*  fp2  = (float*)(ws + alloc((size_t)N * 128 * 4));        // 10.7 MB
  float*  pc   = (float*)(ws + alloc((size_t)N * 128 * 4));        // 10.7 MB
  float*  sig  = (float*)(ws + alloc((size_t)N * 4));
  ushort* fp1  = hbuf;   // fp1 (N x 512 bf16) dead after fp2 GEMM; mixc then overwrites as hbuf

  dim3 blk(256);

  // converts + sigmoid gate
  cvtsig_kernel<<<N / 4, blk, 0, stream>>>((const float4*)x, att_w, att_b, (ushort4*)xb, sig);
  wcvt_kernel<<<dim3(DOUT / 32, DIN / 32), blk, 0, stream>>>(gcn_w, Bt, DIN, DOUT, DIN, 0);
  wcvt_kernel<<<dim3(DOUT / 32, DIN / 32), blk, 0, stream>>>(gat_w, Bt + (size_t)1024 * DIN, DIN, DOUT, DIN, 0);
  wcvt_kernel<<<dim3(512 / 32, DIN / 32), blk, 0, stream>>>(fp_w1, Bt + (size_t)2048 * DIN, DIN, 512, DIN, 0);
  wcvt_kernel<<<dim3(DOUT / 32, DIN / 32), blk, 0, stream>>>(sage_wr, Bt + (size_t)2560 * DIN, DIN, DOUT, DIN, 0);
  wcvt_kernel<<<dim3(DOUT / 32, DIN / 32), blk, 0, stream>>>(sage_wl, Bt + (size_t)3584 * DIN, DIN, DOUT, DIN, 0);
  w2cvt_kernel<<<dim3(128 * 512 / 256), blk, 0, stream>>>(fp_w2, wpw);

  // mega-GEMM (8-phase 256^2): xb @ [gcn_w | gat_w | fp_w1 | sage_wr | sage_wl]
  Epi e1;
  e1.dst[0] = gcnh; e1.dst[1] = Cgat; e1.dst[2] = fp1; e1.dst[3] = xr; e1.dst[4] = xl;
  e1.bias[0] = nullptr; e1.bias[1] = nullptr; e1.bias[2] = fp_b1; e1.bias[3] = nullptr; e1.bias[4] = nullptr;
  e1.nend[0] = 1024; e1.nend[1] = 2048; e1.nend[2] = 2560; e1.nend[3] = 3584; e1.nend[4] = 4608;
  e1.ld[0] = DOUT; e1.ld[1] = DOUT; e1.ld[2] = 512; e1.ld[3] = DOUT; e1.ld[4] = DOUT;
  e1.relu[0] = 0; e1.relu[1] = 0; e1.relu[2] = 1; e1.relu[3] = 0; e1.relu[4] = 0;
  e1.rs = sig;
  gemm8p<<<dim3(MB2 * (NMEGA / 256)), dim3(512), 0, stream>>>(xb, Bt, DIN, NMEGA / 256, e1);

  // fp2 logits GEMM (N=128 padded) — 128^2 ring kernel
  Epi epw;
  epw.dst[0] = fp2; epw.dst[1] = nullptr; epw.dst[2] = nullptr; epw.dst[3] = nullptr; epw.dst[4] = nullptr;
  epw.bias[0] = nullptr; epw.bias[1] = nullptr; epw.bias[2] = nullptr; epw.bias[3] = nullptr; epw.bias[4] = nullptr;
  epw.nend[0] = 1 << 30; epw.nend[1] = 1 << 30; epw.nend[2] = 1 << 30; epw.nend[3] = 1 << 30; epw.nend[4] = 1 << 30;
  epw.ld[0] = 128; epw.ld[1] = 128; epw.ld[2] = 128; epw.ld[3] = 128; epw.ld[4] = 128;
  epw.relu[0] = 0; epw.relu[1] = 0; epw.relu[2] = 0; epw.relu[3] = 0; epw.relu[4] = 0;
  epw.rs = nullptr;
  gemm_bf16<true><<<dim3(MB), blk, 0, stream>>>(fp1, wpw, 512, 1, epw);

  // deep combine: softmax+prefix coefficients -> pc (global), then s_load-driven mixing
  pwprep_kernel<<<B, blk, 0, stream>>>(fp2, fp_b2, pc);
  mixc_kernel<<<dim3(DOUT / 256, B), blk, 0, stream>>>(pc, xr, xl, sage_bl, hbuf);

  // fused tail: all three branches + gate -> out0/out1/out2
  tail_fused<<<B * 4, blk, 0, stream>>>(gcnh, Cgat, hbuf,
                                        gcn_b, sn_g, sn_b,
                                        gat_as, gat_ad, gat_b,
                                        mn_g, mn_b, dn_g, dn_b,
                                        gate_w, gate_b, out, N);
}

// Round 13
// 652.082 us; speedup vs baseline: 1.0746x; 1.0631x over previous
//
#include <hip/hip_runtime.h>
#include <math.h>

static constexpr int S    = 41;
static constexpr int DIN  = 1280;
static constexpr int DOUT = 1024;
static constexpr int HEADS = 4;
static constexpr int HC   = 256;

typedef __attribute__((ext_vector_type(4))) float f32x4;
typedef __attribute__((ext_vector_type(8))) short short8;

__device__ __forceinline__ ushort f2bf(float f) {
  uint u = __float_as_uint(f);
  uint r = u + 0x7fffu + ((u >> 16) & 1u);   // RNE
  return (ushort)(r >> 16);
}
__device__ __forceinline__ float bf2f(ushort u) {
  return __uint_as_float(((uint)u) << 16);
}

__device__ __forceinline__ void gload16(const ushort* g, ushort* l) {
  __builtin_amdgcn_global_load_lds((const __attribute__((address_space(1))) void*)g,
                                   (__attribute__((address_space(3))) void*)l, 16, 0, 0);
}

#define FENCE() asm volatile("" ::: "memory")

// ---------------- reduction helpers ----------------

__device__ __forceinline__ float warpReduceSum(float v) {
#pragma unroll
  for (int off = 32; off; off >>= 1) v += __shfl_down(v, off);
  return v;
}

__device__ __forceinline__ void blockReduce6(float* v) {
  __shared__ float red6[6][4];
  int w = threadIdx.x >> 6, lane = threadIdx.x & 63;
#pragma unroll
  for (int r = 0; r < 6; ++r) v[r] = warpReduceSum(v[r]);
  __syncthreads();
  if (lane == 0) {
#pragma unroll
    for (int r = 0; r < 6; ++r) red6[r][w] = v[r];
  }
  __syncthreads();
#pragma unroll
  for (int r = 0; r < 6; ++r)
    v[r] = red6[r][0] + red6[r][1] + red6[r][2] + red6[r][3];
}

__device__ __forceinline__ void blockReduce3v(float* v) {
  __shared__ float red3[3][4];
  int w = threadIdx.x >> 6, lane = threadIdx.x & 63;
#pragma unroll
  for (int r = 0; r < 3; ++r) v[r] = warpReduceSum(v[r]);
  __syncthreads();
  if (lane == 0) {
#pragma unroll
    for (int r = 0; r < 3; ++r) red3[r][w] = v[r];
  }
  __syncthreads();
#pragma unroll
  for (int r = 0; r < 3; ++r)
    v[r] = red3[r][0] + red3[r][1] + red3[r][2] + red3[r][3];
}

// ---------------- fused x->bf16 convert + sigmoid row gate ----------------

__global__ __launch_bounds__(256) void cvtsig_kernel(
    const float4* __restrict__ x, const float* __restrict__ att_w,
    const float* __restrict__ att_b, ushort4* __restrict__ xb, float* __restrict__ sig)
{
  int row  = blockIdx.x * 4 + (threadIdx.x >> 6);
  int lane = threadIdx.x & 63;
  const float4* xr = x + (size_t)row * (DIN / 4);
  const float4* wr = (const float4*)att_w;
  ushort4* xo = xb + (size_t)row * (DIN / 4);
  float acc = 0.f;
#pragma unroll
  for (int k = 0; k < DIN / 4 / 64; ++k) {   // 5
    float4 a = xr[lane + k * 64];
    float4 w = wr[lane + k * 64];
    acc += a.x * w.x + a.y * w.y + a.z * w.z + a.w * w.w;
    ushort4 o;
    o.x = f2bf(a.x); o.y = f2bf(a.y); o.z = f2bf(a.z); o.w = f2bf(a.w);
    xo[lane + k * 64] = o;
  }
  acc = warpReduceSum(acc);
  if (lane == 0) sig[row] = 1.f / (1.f + expf(-(acc + att_b[0])));
}

// ---------------- weight converts ----------------

__global__ __launch_bounds__(256) void wcvt_kernel(const float* __restrict__ W,
                                                   ushort* __restrict__ out,
                                                   int K, int N, int ostride, int koff) {
  __shared__ float t[32][33];
  int n0 = blockIdx.x * 32, k0 = blockIdx.y * 32;
  int tx = threadIdx.x & 31, ty = threadIdx.x >> 5;
#pragma unroll
  for (int r = 0; r < 4; ++r) {
    int k = ty + r * 8;
    t[k][tx] = W[(size_t)(k0 + k) * N + n0 + tx];
  }
  __syncthreads();
#pragma unroll
  for (int r = 0; r < 4; ++r) {
    int nn = ty + r * 8;
    out[(size_t)(n0 + nn) * ostride + koff + k0 + tx] = f2bf(t[tx][nn]);
  }
}

// wpw[n][k] = n<41 ? bf16(w2[k][n]) : 0   (128 x 512)
__global__ __launch_bounds__(256) void w2cvt_kernel(const float* __restrict__ w2,
                                                    ushort* __restrict__ wpw) {
  int idx = blockIdx.x * 256 + threadIdx.x;
  int n = idx >> 9, k = idx & 511;
  wpw[idx] = (n < S) ? f2bf(w2[(size_t)k * S + n]) : (ushort)0;
}

// ---------------- shared epilogue descriptor ----------------

struct Epi {
  void* dst[5];
  const float* bias[5];
  int nend[5];
  int ld[5];
  int relu[5];
  const float* rs;             // rowscale, branch 0 only
};

// ---------------- 8-phase 256^2 bf16 MFMA GEMM, m201-faithful phase order ----------------
// Per phase: {ds_read subtile; stage half-unit; [counted vmcnt]; s_barrier;
// setprio MFMA setprio; s_barrier}. vmcnt(8) at P1 (publishes ks1(T)) and P3
// (publishes ks0(T+1)); tail vmcnt(4)/(0). XCD-bijective chunked swizzle (m204).
// Chunk-rotation LDS swizzle (rule #21): linear gload_lds dest + inverse-
// permuted global source chunk + permuted read chunk (PMC-verified 0-conflict).

__global__ __launch_bounds__(512, 1) void gemm8p(
    const ushort* __restrict__ A, const ushort* __restrict__ Bt, int K, int nb, Epi e)
{
  __shared__ __align__(16) ushort As[4 * 8192];   // [db*2+ks][256][32] : 64 KB
  __shared__ __align__(16) ushort Bs[4 * 8192];   // 64 KB

  // XCD-bijective chunked swizzle (nwg % 8 != 0 safe)
  int wg;
  {
    const int nwg = gridDim.x;
    const int bid = blockIdx.x;
    const int xcd = bid & 7, lin = bid >> 3;
    const int q = nwg >> 3, r = nwg & 7;
    wg = (xcd < r) ? (xcd * (q + 1) + lin) : (r * (q + 1) + (xcd - r) * q + lin);
  }
  const int bm = (wg / nb) * 256;   // bn-fastest within chunk: A panel L2-resident
  const int bn = (wg % nb) * 256;

  const int tid  = threadIdx.x;
  const int wv   = tid >> 6;          // 0..7
  const int lane = tid & 63;
  const int l16  = lane & 15;
  const int l4   = lane >> 4;
  const int m0   = (wv >> 2) * 128;   // 2 M-strips
  const int n0   = (wv & 3) * 64;     // 4 N-strips

  const int rd0 = wv * 16 + (lane >> 2);         // g=0 row
  const int rd1 = 128 + wv * 16 + (lane >> 2);   // g=1 row
  const int cs0 = ((lane & 3) - ((rd0 >> 1) & 3)) & 3;   // inverse-permuted src chunk
  const int cs1 = ((lane & 3) - ((rd1 >> 1) & 3)) & 3;

  auto stageA = [&](int h, int Tt) {     // h = db*2+ks
    int kof = Tt * 64 + (h & 1) * 32;
    gload16(A + (size_t)(bm + rd0) * K + kof + cs0 * 8, &As[h * 8192 + wv * 512]);
    gload16(A + (size_t)(bm + rd1) * K + kof + cs1 * 8, &As[h * 8192 + (8 + wv) * 512]);
  };
  auto stageB = [&](int h, int Tt) {
    int kof = Tt * 64 + (h & 1) * 32;
    gload16(Bt + (size_t)(bn + rd0) * K + kof + cs0 * 8, &Bs[h * 8192 + wv * 512]);
    gload16(Bt + (size_t)(bn + rd1) * K + kof + cs1 * 8, &Bs[h * 8192 + (8 + wv) * 512]);
  };

  const int rchunk = ((l4 + ((l16 >> 1) & 3)) & 3) * 8;   // read-side rotation

  f32x4 acc[8][4];
#pragma unroll
  for (int i = 0; i < 8; ++i)
#pragma unroll
    for (int j = 0; j < 4; ++j) acc[i][j] = (f32x4)0.f;

  const int NT = K >> 6;   // >= 3

  // prologue: tile0 full + tile1 ks0 (12 loads/thread); publish ks0(0)
  stageA(0, 0); stageB(0, 0);
  stageA(1, 0); stageB(1, 0);
  stageA(2, 1); stageB(2, 1);
  asm volatile("s_waitcnt vmcnt(8)" ::: "memory");
  __builtin_amdgcn_s_barrier();
  FENCE();

  for (int T = 0; T < NT; ++T) {
    const int db = T & 1;
    const int hA = db * 2;          // ks0 half of current buffer
    const int hB = db * 2 + 1;      // ks1 half
    short8 a[4], b[4];

    // ---- P0: read hA(lo-rows)+b; stage A-ks1(T+1); MFMA acc[0..3] ----
#pragma unroll
    for (int i = 0; i < 4; ++i)
      a[i] = *reinterpret_cast<const short8*>(&As[hA * 8192 + (m0 + i * 16 + l16) * 32 + rchunk]);
#pragma unroll
    for (int j = 0; j < 4; ++j)
      b[j] = *reinterpret_cast<const short8*>(&Bs[hA * 8192 + (n0 + j * 16 + l16) * 32 + rchunk]);
    if (T + 1 < NT) stageA((db ^ 1) * 2 + 1, T + 1);
    FENCE(); __builtin_amdgcn_s_barrier(); FENCE();
    __builtin_amdgcn_s_setprio(1);
#pragma unroll
    for (int i = 0; i < 4; ++i)
#pragma unroll
      for (int j = 0; j < 4; ++j)
        acc[i][j] = __builtin_amdgcn_mfma_f32_16x16x32_bf16(a[i], b[j], acc[i][j], 0, 0, 0);
    __builtin_amdgcn_s_setprio(0);
    FENCE(); __builtin_amdgcn_s_barrier(); FENCE();

    // ---- P1: read hA(hi-rows); stage B-ks1(T+1); vmcnt publishes ks1(T); MFMA acc[4..7] ----
#pragma unroll
    for (int i = 0; i < 4; ++i)
      a[i] = *reinterpret_cast<const short8*>(&As[hA * 8192 + (m0 + 64 + i * 16 + l16) * 32 + rchunk]);
    if (T + 1 < NT) {
      stageB((db ^ 1) * 2 + 1, T + 1);
      asm volatile("s_waitcnt vmcnt(8)" ::: "memory");
    } else {
      asm volatile("s_waitcnt vmcnt(0)" ::: "memory");
    }
    FENCE(); __builtin_amdgcn_s_barrier(); FENCE();
    __builtin_amdgcn_s_setprio(1);
#pragma unroll
    for (int i = 0; i < 4; ++i)
#pragma unroll
      for (int j = 0; j < 4; ++j)
        acc[4 + i][j] = __builtin_amdgcn_mfma_f32_16x16x32_bf16(a[i], b[j], acc[4 + i][j], 0, 0, 0);
    __builtin_amdgcn_s_setprio(0);
    FENCE(); __builtin_amdgcn_s_barrier(); FENCE();

    // ---- P2: read hB(lo-rows)+b; stage A-ks0(T+2) into freed hA; MFMA acc[0..3] ----
#pragma unroll
    for (int i = 0; i < 4; ++i)
      a[i] = *reinterpret_cast<const short8*>(&As[hB * 8192 + (m0 + i * 16 + l16) * 32 + rchunk]);
#pragma unroll
    for (int j = 0; j < 4; ++j)
      b[j] = *reinterpret_cast<const short8*>(&Bs[hB * 8192 + (n0 + j * 16 + l16) * 32 + rchunk]);
    if (T + 2 < NT) stageA(hA, T + 2);
    FENCE(); __builtin_amdgcn_s_barrier(); FENCE();
    __builtin_amdgcn_s_setprio(1);
#pragma unroll
    for (int i = 0; i < 4; ++i)
#pragma unroll
      for (int j = 0; j < 4; ++j)
        acc[i][j] = __builtin_amdgcn_mfma_f32_16x16x32_bf16(a[i], b[j], acc[i][j], 0, 0, 0);
    __builtin_amdgcn_s_setprio(0);
    FENCE(); __builtin_amdgcn_s_barrier(); FENCE();

    // ---- P3: read hB(hi-rows); stage B-ks0(T+2); vmcnt publishes ks0(T+1); MFMA acc[4..7] ----
#pragma unroll
    for (int i = 0; i < 4; ++i)
      a[i] = *reinterpret_cast<const short8*>(&As[hB * 8192 + (m0 + 64 + i * 16 + l16) * 32 + rchunk]);
    if (T + 2 < NT) {
      stageB(hA, T + 2);
      asm volatile("s_waitcnt vmcnt(8)" ::: "memory");
    } else if (T + 1 < NT) {
      asm volatile("s_waitcnt vmcnt(4)" ::: "memory");
    }
    FENCE(); __builtin_amdgcn_s_barrier(); FENCE();
    __builtin_amdgcn_s_setprio(1);
#pragma unroll
    for (int i = 0; i < 4; ++i)
#pragma unroll
      for (int j = 0; j < 4; ++j)
        acc[4 + i][j] = __builtin_amdgcn_mfma_f32_16x16x32_bf16(a[i], b[j], acc[4 + i][j], 0, 0, 0);
    __builtin_amdgcn_s_setprio(0);
    FENCE(); __builtin_amdgcn_s_barrier(); FENCE();
  }

  void* dstv; const float* bias; const float* rs = nullptr; int ldc, cb, relu;
  if (bn < e.nend[0])      { dstv = e.dst[0]; ldc = e.ld[0]; cb = bn;             bias = e.bias[0]; relu = e.relu[0]; rs = e.rs; }
  else if (bn < e.nend[1]) { dstv = e.dst[1]; ldc = e.ld[1]; cb = bn - e.nend[0]; bias = e.bias[1]; relu = e.relu[1]; }
  else if (bn < e.nend[2]) { dstv = e.dst[2]; ldc = e.ld[2]; cb = bn - e.nend[1]; bias = e.bias[2]; relu = e.relu[2]; }
  else if (bn < e.nend[3]) { dstv = e.dst[3]; ldc = e.ld[3]; cb = bn - e.nend[2]; bias = e.bias[3]; relu = e.relu[3]; }
  else                     { dstv = e.dst[4]; ldc = e.ld[4]; cb = bn - e.nend[3]; bias = e.bias[4]; relu = e.relu[4]; }

#pragma unroll
  for (int i = 0; i < 8; ++i) {
    int mbase = bm + m0 + i * 16 + l4 * 4;
    float rsv[4];
#pragma unroll
    for (int r = 0; r < 4; ++r) rsv[r] = rs ? rs[mbase + r] : 1.f;
#pragma unroll
    for (int j = 0; j < 4; ++j) {
      int col = cb + n0 + j * 16 + l16;
      float bv = bias ? bias[col] : 0.f;
#pragma unroll
      for (int r = 0; r < 4; ++r) {
        float t = acc[i][j][r] * rsv[r] + bv;
        if (relu) t = fmaxf(t, 0.f);
        ((ushort*)dstv)[(size_t)(mbase + r) * ldc + col] = f2bf(t);
      }
    }
  }
}

// ---------------- 128x128 bf16 MFMA GEMM (fp2 GEMM; r10-verified ring) ----------------

template<bool F32OUT>
__global__ __launch_bounds__(256) void gemm_bf16(
    const ushort* __restrict__ A, const ushort* __restrict__ Bt, int K, int nb, Epi e)
{
  __shared__ __align__(16) ushort As[3][128 * 32];
  __shared__ __align__(16) ushort Bs[3][128 * 32];

  const int bid = blockIdx.x;
  const int bm  = (bid / nb) * 128;
  const int bn  = (bid % nb) * 128;

  const int tid  = threadIdx.x;
  const int w    = tid >> 6;
  const int lane = tid & 63;
  const int l16  = lane & 15;
  const int l4   = lane >> 4;
  const int m0   = (w >> 1) * 64;
  const int n0   = (w & 1) * 64;

  const int rloc = lane >> 2;
  const int cpos = lane & 3;
  const int cdat = (cpos - (rloc >> 1)) & 3;
  const int srow = w * 32 + rloc;
  const int scol = cdat * 8;

  f32x4 acc[4][4];
#pragma unroll
  for (int i = 0; i < 4; ++i)
#pragma unroll
    for (int j = 0; j < 4; ++j) acc[i][j] = (f32x4)0.f;

  const ushort* pA0 = A  + (size_t)(bm + srow) * K + scol;
  const ushort* pA1 = A  + (size_t)(bm + srow + 16) * K + scol;
  const ushort* pB0 = Bt + (size_t)(bn + srow) * K + scol;
  const ushort* pB1 = Bt + (size_t)(bn + srow + 16) * K + scol;

  auto stage = [&](int buf, int kt) {
    gload16(pA0 + kt, &As[buf][w * 1024]);
    gload16(pA1 + kt, &As[buf][w * 1024 + 512]);
    gload16(pB0 + kt, &Bs[buf][w * 1024]);
    gload16(pB1 + kt, &Bs[buf][w * 1024 + 512]);
  };

  const int rchunk = ((l4 + (l16 >> 1)) & 3) * 8;

  const int nsteps = K >> 5;
  stage(0, 0); stage(1, 32); stage(2, 64);

  for (int t = 0; t < nsteps; ++t) {
    if (t == 0)                asm volatile("s_waitcnt vmcnt(8)" ::: "memory");
    else if (t == nsteps - 1)  asm volatile("s_waitcnt vmcnt(0)" ::: "memory");
    else                       asm volatile("s_waitcnt vmcnt(4)" ::: "memory");
    __builtin_amdgcn_s_barrier();
    FENCE();

    if (t >= 1 && t + 2 < nsteps) stage((t + 2) % 3, (t + 2) * 32);

    const int cur = t % 3;
    short8 a[4], b[4];
#pragma unroll
    for (int i = 0; i < 4; ++i)
      a[i] = *reinterpret_cast<const short8*>(&As[cur][(m0 + i * 16 + l16) * 32 + rchunk]);
#pragma unroll
    for (int j = 0; j < 4; ++j)
      b[j] = *reinterpret_cast<const short8*>(&Bs[cur][(n0 + j * 16 + l16) * 32 + rchunk]);
    __builtin_amdgcn_s_setprio(1);
#pragma unroll
    for (int i = 0; i < 4; ++i)
#pragma unroll
      for (int j = 0; j < 4; ++j)
        acc[i][j] = __builtin_amdgcn_mfma_f32_16x16x32_bf16(a[i], b[j], acc[i][j], 0, 0, 0);
    __builtin_amdgcn_s_setprio(0);
  }

  void* dstv; const float* bias; const float* rs = nullptr; int ldc, cb, relu;
  if (bn < e.nend[0])      { dstv = e.dst[0]; ldc = e.ld[0]; cb = bn;             bias = e.bias[0]; relu = e.relu[0]; rs = e.rs; }
  else if (bn < e.nend[1]) { dstv = e.dst[1]; ldc = e.ld[1]; cb = bn - e.nend[0]; bias = e.bias[1]; relu = e.relu[1]; }
  else if (bn < e.nend[2]) { dstv = e.dst[2]; ldc = e.ld[2]; cb = bn - e.nend[1]; bias = e.bias[2]; relu = e.relu[2]; }
  else if (bn < e.nend[3]) { dstv = e.dst[3]; ldc = e.ld[3]; cb = bn - e.nend[2]; bias = e.bias[3]; relu = e.relu[3]; }
  else                     { dstv = e.dst[4]; ldc = e.ld[4]; cb = bn - e.nend[3]; bias = e.bias[4]; relu = e.relu[4]; }

#pragma unroll
  for (int i = 0; i < 4; ++i) {
    int mbase = bm + m0 + i * 16 + l4 * 4;
    float rsv[4];
#pragma unroll
    for (int r = 0; r < 4; ++r) rsv[r] = rs ? rs[mbase + r] : 1.f;
#pragma unroll
    for (int j = 0; j < 4; ++j) {
      int col = cb + n0 + j * 16 + l16;
      float bv = bias ? bias[col] : 0.f;
#pragma unroll
      for (int r = 0; r < 4; ++r) {
        float t = acc[i][j][r] * rsv[r] + bv;
        if (relu) t = fmaxf(t, 0.f);
        if (F32OUT) ((float*)dstv)[(size_t)(mbase + r) * ldc + col] = t;
        else        ((ushort*)dstv)[(size_t)(mbase + r) * ldc + col] = f2bf(t);
      }
    }
  }
}

// ---------------- pwprep: softmax rows + prefix-mean rows -> global pc (f32) ----------------

__global__ __launch_bounds__(256) void pwprep_kernel(
    const float* __restrict__ fp2, const float* __restrict__ fp_b2,
    float* __restrict__ pc)
{
  int b = blockIdx.x;
  int tid = threadIdx.x, wv = tid >> 6, lane = tid & 63;
  __shared__ float pws[S][S];
  for (int i = wv; i < S; i += 4) {
    float v = (lane < S) ? (fp2[(size_t)(b * S + i) * 128 + lane] + fp_b2[lane]) : -1e30f;
    float m = v;
#pragma unroll
    for (int off = 32; off; off >>= 1) m = fmaxf(m, __shfl_xor(m, off));
    float e = (lane < S) ? expf(v - m) : 0.f;
    float sum = e;
#pragma unroll
    for (int off = 32; off; off >>= 1) sum += __shfl_xor(sum, off);
    if (lane < S) {
      float p = e / sum;
      pws[i][lane] = p;
      pc[((size_t)b * S + i) * 128 + lane] = p;
    }
  }
  __syncthreads();
  if (tid < S) {
    float run = 0.f;
    for (int i = 0; i < S; ++i) {
      pc[((size_t)b * S + i) * 128 + 64 + tid] = (i > 0) ? run / (float)i : 0.f;
      run += pws[i][tid];
    }
  }
}

// ---------------- mixc: sage = P@xr + CPW@xl + bl, coefficients via wave-uniform s_load ----------------

__global__ __launch_bounds__(256) void mixc_kernel(
    const float* __restrict__ pc, const ushort* __restrict__ xr,
    const ushort* __restrict__ xl, const float* __restrict__ sage_bl,
    ushort* __restrict__ hbuf)
{
  int b  = blockIdx.y;
  int d0 = blockIdx.x * 256;    // grid.x = DOUT/256 = 4
  int tid = threadIdx.x;

  float xrv[S], xlv[S];
  const ushort* xrp = xr + (size_t)(b * S) * DOUT + d0 + tid;
  const ushort* xlp = xl + (size_t)(b * S) * DOUT + d0 + tid;
#pragma unroll
  for (int j = 0; j < S; ++j) {
    xrv[j] = bf2f(xrp[(size_t)j * DOUT]);
    xlv[j] = bf2f(xlp[(size_t)j * DOUT]);
  }
  float bl = sage_bl[d0 + tid];
  ushort* op = hbuf + (size_t)(b * S) * DOUT + d0 + tid;
  const float* pcb = pc + (size_t)(b * S) * 128;
  for (int i = 0; i < S; ++i) {
    const float* row = pcb + (size_t)i * 128;   // wave-uniform -> s_load path
    float acc = bl;
#pragma unroll
    for (int j = 0; j < S; ++j)
      acc += row[j] * xrv[j] + row[64 + j] * xlv[j];
    op[(size_t)i * DOUT] = f2bf(acc);
  }
}

// ---------------- fused tail ----------------

__device__ __forceinline__ float dinv_local(int j) {
  return rsqrtf((j == 0 || j == S - 1) ? 3.f : 5.f);
}

__global__ __launch_bounds__(256) void tail_fused(
    const ushort* __restrict__ gcnh, const ushort* __restrict__ Cgat,
    const ushort* __restrict__ hbuf,
    const float* __restrict__ gcn_b, const float* __restrict__ sn_g, const float* __restrict__ sn_b,
    const float* __restrict__ gat_as, const float* __restrict__ gat_ad, const float* __restrict__ gat_b,
    const float* __restrict__ mn_g, const float* __restrict__ mn_b,
    const float* __restrict__ dn_g, const float* __restrict__ dn_b,
    const float* __restrict__ gw, const float* __restrict__ gb,
    float* __restrict__ out, int N)
{
  int b  = blockIdx.x >> 2;
  int rb = blockIdx.x & 3;
  int lo = rb * 13;
  int cnt = (rb < 3) ? 13 : 2;
  size_t OUT = (size_t)N * DOUT;
  int tid = threadIdx.x;
  int wv = tid >> 6, lane = tid & 63;
  int d0 = tid * 4;
  int head = tid >> 6;

  __shared__ __align__(16) ushort hs[13][DOUT];
  __shared__ float alpha[13][13][HEADS];
  __shared__ float als_l[13][HEADS], ald_l[13][HEADS];

  for (int r = 0; r < cnt; ++r) {
    const ushort4* src = (const ushort4*)(Cgat + (size_t)(b * S + lo + r) * DOUT);
    ((ushort4*)hs[r])[tid] = src[tid];
  }
  __syncthreads();

  {
    const float4* a4 = (const float4*)(gat_as + wv * HC);
    const float4* d4 = (const float4*)(gat_ad + wv * HC);
    float4 av = a4[lane], dv = d4[lane];
    for (int s = 0; s < cnt; ++s) {
      ushort4 hv4 = ((const ushort4*)&hs[s][wv * HC])[lane];
      float h0 = bf2f(hv4.x), h1 = bf2f(hv4.y), h2 = bf2f(hv4.z), h3 = bf2f(hv4.w);
      float a = h0 * av.x + h1 * av.y + h2 * av.z + h3 * av.w;
      float d = h0 * dv.x + h1 * dv.y + h2 * dv.z + h3 * dv.w;
      a = warpReduceSum(a);
      d = warpReduceSum(d);
      if (lane == 0) { als_l[s][wv] = a; ald_l[s][wv] = d; }
    }
  }
  __syncthreads();

  if (tid < cnt * HEADS) {
    int t = tid >> 2, hd = tid & 3;
    float myald = ald_l[t][hd];
    float m = -1e30f;
    for (int s = 0; s < cnt; ++s) {
      float v = als_l[s][hd] + myald;
      v = (v > 0.f) ? v : 0.2f * v;
      m = fmaxf(m, v);
    }
    float den = 0.f;
    for (int s = 0; s < cnt; ++s) {
      float v = als_l[s][hd] + myald;
      v = (v > 0.f) ? v : 0.2f * v;
      float ev = expf(v - m) * ((s == t) ? 1.f : 2.f);  // duplicate edges -> weight 2
      alpha[t][s][hd] = ev;
      den += ev;
    }
    float inv = 1.f / den;
    for (int s = 0; s < cnt; ++s) alpha[t][s][hd] *= inv;
  }
  __syncthreads();

  float4 gcnb4 = *(const float4*)(gcn_b + d0);
  float4 sng4  = *(const float4*)(sn_g + d0);
  float4 snb4  = *(const float4*)(sn_b + d0);
  float4 gatb4 = *(const float4*)(gat_b + d0);
  float4 mng4  = *(const float4*)(mn_g + d0);
  float4 mnb4  = *(const float4*)(mn_b + d0);
  float4 dng4  = *(const float4*)(dn_g + d0);
  float4 dnb4  = *(const float4*)(dn_b + d0);
  float gwsh[4][3], gwga[4][3], gwsa[4][3];
#pragma unroll
  for (int q = 0; q < 4; ++q)
#pragma unroll
    for (int c = 0; c < 3; ++c) {
      gwsh[q][c] = gw[(size_t)(d0 + q) * 3 + c];
      gwga[q][c] = gw[(size_t)(DOUT + d0 + q) * 3 + c];
      gwsa[q][c] = gw[(size_t)(2 * DOUT + d0 + q) * 3 + c];
    }

  for (int t = 0; t < cnt; ++t) {
    int i = lo + t;
    size_t n = (size_t)(b * S + i);

    float di = dinv_local(i);
    float wc = di * di;
    float wl = (i > 0)     ? 2.f * di * dinv_local(i - 1) : 0.f;
    float wr = (i < S - 1) ? 2.f * di * dinv_local(i + 1) : 0.f;
    const ushort* hc = gcnh + n * DOUT + d0;
    ushort4 c4  = *(const ushort4*)hc;
    ushort4 lft = (i > 0)     ? *(const ushort4*)(hc - DOUT) : ushort4{0, 0, 0, 0};
    ushort4 rgt = (i < S - 1) ? *(const ushort4*)(hc + DOUT) : ushort4{0, 0, 0, 0};
    const ushort* cp = (const ushort*)&c4;
    const ushort* lp = (const ushort*)&lft;
    const ushort* rp = (const ushort*)&rgt;
    const float* gbp = (const float*)&gcnb4;
    float sh[4];
#pragma unroll
    for (int q = 0; q < 4; ++q)
      sh[q] = wc * bf2f(cp[q]) + wl * bf2f(lp[q]) + wr * bf2f(rp[q]) + gbp[q];

    float ga[4] = {0.f, 0.f, 0.f, 0.f};
    for (int si = 0; si < cnt; ++si) {
      float aj = alpha[t][si][head];
      ushort4 hv = *(const ushort4*)&hs[si][d0];
      ga[0] += aj * bf2f(hv.x);
      ga[1] += aj * bf2f(hv.y);
      ga[2] += aj * bf2f(hv.z);
      ga[3] += aj * bf2f(hv.w);
    }
    const float* gab = (const float*)&gatb4;
#pragma unroll
    for (int q = 0; q < 4; ++q) ga[q] += gab[q];

    ushort4 s4v = *(const ushort4*)(hbuf + n * DOUT + d0);
    const ushort* sp = (const ushort*)&s4v;
    float sa[4];
#pragma unroll
    for (int q = 0; q < 4; ++q) sa[q] = bf2f(sp[q]);

    float red[6] = {0.f, 0.f, 0.f, 0.f, 0.f, 0.f};
#pragma unroll
    for (int q = 0; q < 4; ++q) {
      red[0] += sh[q]; red[1] += sh[q] * sh[q];
      red[2] += ga[q]; red[3] += ga[q] * ga[q];
      red[4] += sa[q]; red[5] += sa[q] * sa[q];
    }
    blockReduce6(red);
    float mu0 = red[0] * (1.f / DOUT), r0 = rsqrtf(red[1] * (1.f / DOUT) - mu0 * mu0 + 1e-5f);
    float mu1 = red[2] * (1.f / DOUT), r1 = rsqrtf(red[3] * (1.f / DOUT) - mu1 * mu1 + 1e-5f);
    float mu2 = red[4] * (1.f / DOUT), r2 = rsqrtf(red[5] * (1.f / DOUT) - mu2 * mu2 + 1e-5f);

    const float* sngp = (const float*)&sng4; const float* snbp = (const float*)&snb4;
    const float* mngp = (const float*)&mng4; const float* mnbp = (const float*)&mnb4;
    const float* dngp = (const float*)&dng4; const float* dnbp = (const float*)&dnb4;
    float shn[4], gan[4], san[4];
#pragma unroll
    for (int q = 0; q < 4; ++q) {
      shn[q] = (sh[q] - mu0) * r0 * sngp[q] + snbp[q];
      gan[q] = (ga[q] - mu1) * r1 * mngp[q] + mnbp[q];
      san[q] = (sa[q] - mu2) * r2 * dngp[q] + dnbp[q];
    }

    float p[3] = {0.f, 0.f, 0.f};
#pragma unroll
    for (int q = 0; q < 4; ++q) {
#pragma unroll
      for (int c = 0; c < 3; ++c)
        p[c] += shn[q] * gwsh[q][c] + gan[q] * gwga[q][c] + san[q] * gwsa[q][c];
    }
    blockReduce3v(p);
    float l0 = p[0] + gb[0], l1 = p[1] + gb[1], l2 = p[2] + gb[2];
    float m = fmaxf(l0, fmaxf(l1, l2));
    float e0 = expf(l0 - m), e1 = expf(l1 - m), e2 = expf(l2 - m);
    float inv = 1.f / (e0 + e1 + e2);
    float g0 = e0 * inv, g1 = e1 * inv, g2 = e2 * inv;

    float4 o0, o1, o2;
    float* o0p = (float*)&o0; float* o1p = (float*)&o1; float* o2p = (float*)&o2;
#pragma unroll
    for (int q = 0; q < 4; ++q) {
      o0p[q] = shn[q];
      o1p[q] = gan[q];
      o2p[q] = g0 * shn[q] + g1 * gan[q] + g2 * san[q];
    }
    *(float4*)(out + n * DOUT + d0)           = o0;
    *(float4*)(out + OUT + n * DOUT + d0)     = o1;
    *(float4*)(out + 2 * OUT + n * DOUT + d0) = o2;
  }
}

// ---------------- launch ----------------

extern "C" void kernel_launch(void* const* d_in, const int* in_sizes, int n_in,
                              void* d_out, int out_size, void* d_ws, size_t ws_size,
                              hipStream_t stream) {
  const float* x       = (const float*)d_in[0];
  const float* att_w   = (const float*)d_in[1];
  const float* att_b   = (const float*)d_in[2];
  const float* gcn_w   = (const float*)d_in[3];
  const float* gcn_b   = (const float*)d_in[4];
  const float* sn_g    = (const float*)d_in[5];
  const float* sn_b    = (const float*)d_in[6];
  const float* gat_w   = (const float*)d_in[7];
  const float* gat_as  = (const float*)d_in[8];
  const float* gat_ad  = (const float*)d_in[9];
  const float* gat_b   = (const float*)d_in[10];
  const float* mn_g    = (const float*)d_in[11];
  const float* mn_b    = (const float*)d_in[12];
  const float* sage_wl = (const float*)d_in[13];
  const float* sage_bl = (const float*)d_in[14];
  const float* sage_wr = (const float*)d_in[15];
  const float* fp_w1   = (const float*)d_in[16];
  const float* fp_b1   = (const float*)d_in[17];
  const float* fp_w2   = (const float*)d_in[18];
  const float* fp_b2   = (const float*)d_in[19];
  const float* dn_g    = (const float*)d_in[20];
  const float* dn_b    = (const float*)d_in[21];
  const float* gate_w  = (const float*)d_in[22];
  const float* gate_b  = (const float*)d_in[23];

  const int B = in_sizes[0] / (S * DIN);   // 512
  const int N = B * S;                     // 20992 = 82*256
  const int MB  = N / 128;                 // 164 (fp2 GEMM)
  const int MB2 = N / 256;                 // 82  (mega GEMM)
  const int NMEGA = 4608;                  // [gcn 1024 | gat 1024 | fp1 512 | xr 1024 | xl 1024]
  float* out = (float*)d_out;

  char* ws = (char*)d_ws;
  size_t off = 0;
  auto alloc = [&](size_t bytes) { size_t p = off; off += (bytes + 255) & ~(size_t)255; return p; };
  ushort* xb   = (ushort*)(ws + alloc((size_t)N * DIN * 2));       // 53.7 MB
  ushort* Bt   = (ushort*)(ws + alloc((size_t)NMEGA * DIN * 2));   // 11.8 MB
  ushort* wpw  = (ushort*)(ws + alloc((size_t)128 * 512 * 2));     // 0.13 MB
  ushort* gcnh = (ushort*)(ws + alloc((size_t)N * DOUT * 2));      // 43 MB
  ushort* Cgat = (ushort*)(ws + alloc((size_t)N * DOUT * 2));      // 43 MB
  ushort* xr   = (ushort*)(ws + alloc((size_t)N * DOUT * 2));      // 43 MB
  ushort* xl   = (ushort*)(ws + alloc((size_t)N * DOUT * 2));      // 43 MB
  ushort* hbuf = (ushort*)(ws + alloc((size_t)N * DOUT * 2));      // 43 MB (fp1 aliases; mixc overwrites)
  float*  fp2  = (float*)(ws + alloc((size_t)N * 128 * 4));        // 10.7 MB
  float*  pc   = (float*)(ws + alloc((size_t)N * 128 * 4));        // 10.7 MB
  float*  sig  = (float*)(ws + alloc((size_t)N * 4));
  ushort* fp1  = hbuf;   // fp1 (N x 512 bf16) dead after fp2 GEMM; mixc then overwrites as hbuf

  dim3 blk(256);

  // converts + sigmoid gate
  cvtsig_kernel<<<N / 4, blk, 0, stream>>>((const float4*)x, att_w, att_b, (ushort4*)xb, sig);
  wcvt_kernel<<<dim3(DOUT / 32, DIN / 32), blk, 0, stream>>>(gcn_w, Bt, DIN, DOUT, DIN, 0);
  wcvt_kernel<<<dim3(DOUT / 32, DIN / 32), blk, 0, stream>>>(gat_w, Bt + (size_t)1024 * DIN, DIN, DOUT, DIN, 0);
  wcvt_kernel<<<dim3(512 / 32, DIN / 32), blk, 0, stream>>>(fp_w1, Bt + (size_t)2048 * DIN, DIN, 512, DIN, 0);
  wcvt_kernel<<<dim3(DOUT / 32, DIN / 32), blk, 0, stream>>>(sage_wr, Bt + (size_t)2560 * DIN, DIN, DOUT, DIN, 0);
  wcvt_kernel<<<dim3(DOUT / 32, DIN / 32), blk, 0, stream>>>(sage_wl, Bt + (size_t)3584 * DIN, DIN, DOUT, DIN, 0);
  w2cvt_kernel<<<dim3(128 * 512 / 256), blk, 0, stream>>>(fp_w2, wpw);

  // mega-GEMM (8-phase 256^2, m201 phase order + XCD swizzle)
  Epi e1;
  e1.dst[0] = gcnh; e1.dst[1] = Cgat; e1.dst[2] = fp1; e1.dst[3] = xr; e1.dst[4] = xl;
  e1.bias[0] = nullptr; e1.bias[1] = nullptr; e1.bias[2] = fp_b1; e1.bias[3] = nullptr; e1.bias[4] = nullptr;
  e1.nend[0] = 1024; e1.nend[1] = 2048; e1.nend[2] = 2560; e1.nend[3] = 3584; e1.nend[4] = 4608;
  e1.ld[0] = DOUT; e1.ld[1] = DOUT; e1.ld[2] = 512; e1.ld[3] = DOUT; e1.ld[4] = DOUT;
  e1.relu[0] = 0; e1.relu[1] = 0; e1.relu[2] = 1; e1.relu[3] = 0; e1.relu[4] = 0;
  e1.rs = sig;
  gemm8p<<<dim3(MB2 * (NMEGA / 256)), dim3(512), 0, stream>>>(xb, Bt, DIN, NMEGA / 256, e1);

  // fp2 logits GEMM (N=128 padded) — 128^2 ring kernel
  Epi epw;
  epw.dst[0] = fp2; epw.dst[1] = nullptr; epw.dst[2] = nullptr; epw.dst[3] = nullptr; epw.dst[4] = nullptr;
  epw.bias[0] = nullptr; epw.bias[1] = nullptr; epw.bias[2] = nullptr; epw.bias[3] = nullptr; epw.bias[4] = nullptr;
  epw.nend[0] = 1 << 30; epw.nend[1] = 1 << 30; epw.nend[2] = 1 << 30; epw.nend[3] = 1 << 30; epw.nend[4] = 1 << 30;
  epw.ld[0] = 128; epw.ld[1] = 128; epw.ld[2] = 128; epw.ld[3] = 128; epw.ld[4] = 128;
  epw.relu[0] = 0; epw.relu[1] = 0; epw.relu[2] = 0; epw.relu[3] = 0; epw.relu[4] = 0;
  epw.rs = nullptr;
  gemm_bf16<true><<<dim3(MB), blk, 0, stream>>>(fp1, wpw, 512, 1, epw);

  // deep combine: softmax+prefix coefficients -> pc (global), then s_load-driven mixing
  pwprep_kernel<<<B, blk, 0, stream>>>(fp2, fp_b2, pc);
  mixc_kernel<<<dim3(DOUT / 256, B), blk, 0, stream>>>(pc, xr, xl, sage_bl, hbuf);

  // fused tail: all three branches + gate -> out0/out1/out2
  tail_fused<<<B * 4, blk, 0, stream>>>(gcnh, Cgat, hbuf,
                                        gcn_b, sn_g, sn_b,
                                        gat_as, gat_ad, gat_b,
                                        mn_g, mn_b, dn_g, dn_b,
                                        gate_w, gate_b, out, N);
}

// Round 14
// 639.614 us; speedup vs baseline: 1.0955x; 1.0195x over previous
//
#include <hip/hip_runtime.h>
#include <math.h>

static constexpr int S    = 41;
static constexpr int DIN  = 1280;
static constexpr int DOUT = 1024;
static constexpr int HEADS = 4;
static constexpr int HC   = 256;

typedef __attribute__((ext_vector_type(4))) float f32x4;
typedef __attribute__((ext_vector_type(8))) short short8;

__device__ __forceinline__ ushort f2bf(float f) {
  uint u = __float_as_uint(f);
  uint r = u + 0x7fffu + ((u >> 16) & 1u);   // RNE
  return (ushort)(r >> 16);
}
__device__ __forceinline__ float bf2f(ushort u) {
  return __uint_as_float(((uint)u) << 16);
}

__device__ __forceinline__ void gload16(const ushort* g, ushort* l) {
  __builtin_amdgcn_global_load_lds((const __attribute__((address_space(1))) void*)g,
                                   (__attribute__((address_space(3))) void*)l, 16, 0, 0);
}

#define FENCE() asm volatile("" ::: "memory")

// ---------------- reduction helpers ----------------

__device__ __forceinline__ float warpReduceSum(float v) {
#pragma unroll
  for (int off = 32; off; off >>= 1) v += __shfl_down(v, off);
  return v;
}

// ---------------- fused x->bf16 convert + sigmoid row gate ----------------

__global__ __launch_bounds__(256) void cvtsig_kernel(
    const float4* __restrict__ x, const float* __restrict__ att_w,
    const float* __restrict__ att_b, ushort4* __restrict__ xb, float* __restrict__ sig)
{
  int row  = blockIdx.x * 4 + (threadIdx.x >> 6);
  int lane = threadIdx.x & 63;
  const float4* xr = x + (size_t)row * (DIN / 4);
  const float4* wr = (const float4*)att_w;
  ushort4* xo = xb + (size_t)row * (DIN / 4);
  float acc = 0.f;
#pragma unroll
  for (int k = 0; k < DIN / 4 / 64; ++k) {   // 5
    float4 a = xr[lane + k * 64];
    float4 w = wr[lane + k * 64];
    acc += a.x * w.x + a.y * w.y + a.z * w.z + a.w * w.w;
    ushort4 o;
    o.x = f2bf(a.x); o.y = f2bf(a.y); o.z = f2bf(a.z); o.w = f2bf(a.w);
    xo[lane + k * 64] = o;
  }
  acc = warpReduceSum(acc);
  if (lane == 0) sig[row] = 1.f / (1.f + expf(-(acc + att_b[0])));
}

// ---------------- weight converts ----------------

// 4 weights, all [DIN][DOUT] -> out[n][k], row-stride DIN. blockIdx.z picks weight.
struct W4 { const float* src[4]; ushort* dst[4]; };

__global__ __launch_bounds__(256) void wcvt4_kernel(W4 w) {
  __shared__ float t[32][33];
  const float* W = w.src[blockIdx.z];
  ushort* out = w.dst[blockIdx.z];
  int n0 = blockIdx.x * 32, k0 = blockIdx.y * 32;
  int tx = threadIdx.x & 31, ty = threadIdx.x >> 5;
#pragma unroll
  for (int r = 0; r < 4; ++r) {
    int k = ty + r * 8;
    t[k][tx] = W[(size_t)(k0 + k) * DOUT + n0 + tx];
  }
  __syncthreads();
#pragma unroll
  for (int r = 0; r < 4; ++r) {
    int nn = ty + r * 8;
    out[(size_t)(n0 + nn) * DIN + k0 + tx] = f2bf(t[tx][nn]);
  }
}

__global__ __launch_bounds__(256) void wcvt_kernel(const float* __restrict__ W,
                                                   ushort* __restrict__ out,
                                                   int K, int N, int ostride, int koff) {
  __shared__ float t[32][33];
  int n0 = blockIdx.x * 32, k0 = blockIdx.y * 32;
  int tx = threadIdx.x & 31, ty = threadIdx.x >> 5;
#pragma unroll
  for (int r = 0; r < 4; ++r) {
    int k = ty + r * 8;
    t[k][tx] = W[(size_t)(k0 + k) * N + n0 + tx];
  }
  __syncthreads();
#pragma unroll
  for (int r = 0; r < 4; ++r) {
    int nn = ty + r * 8;
    out[(size_t)(n0 + nn) * ostride + koff + k0 + tx] = f2bf(t[tx][nn]);
  }
}

// wpw[n][k] = n<41 ? bf16(w2[k][n]) : 0   (128 x 512)
__global__ __launch_bounds__(256) void w2cvt_kernel(const float* __restrict__ w2,
                                                    ushort* __restrict__ wpw) {
  int idx = blockIdx.x * 256 + threadIdx.x;
  int n = idx >> 9, k = idx & 511;
  wpw[idx] = (n < S) ? f2bf(w2[(size_t)k * S + n]) : (ushort)0;
}

// ---------------- shared epilogue descriptor ----------------

struct Epi {
  void* dst[5];
  const float* bias[5];
  int nend[5];
  int ld[5];
  int relu[5];
  const float* rs;             // rowscale, branch 0 only
};

// ---------------- 8-phase 256^2 bf16 MFMA GEMM, m201 phase order, T-unrolled x2 ----------------

__global__ __launch_bounds__(512, 1) void gemm8p(
    const ushort* __restrict__ A, const ushort* __restrict__ Bt, int K, int nb, Epi e)
{
  __shared__ __align__(16) ushort As[4 * 8192];   // [db*2+ks][256][32] : 64 KB
  __shared__ __align__(16) ushort Bs[4 * 8192];   // 64 KB

  // XCD-bijective chunked swizzle (nwg % 8 != 0 safe)
  int wg;
  {
    const int nwg = gridDim.x;
    const int bid = blockIdx.x;
    const int xcd = bid & 7, lin = bid >> 3;
    const int q = nwg >> 3, r = nwg & 7;
    wg = (xcd < r) ? (xcd * (q + 1) + lin) : (r * (q + 1) + (xcd - r) * q + lin);
  }
  const int bm = (wg / nb) * 256;
  const int bn = (wg % nb) * 256;

  const int tid  = threadIdx.x;
  const int wv   = tid >> 6;
  const int lane = tid & 63;
  const int l16  = lane & 15;
  const int l4   = lane >> 4;
  const int m0   = (wv >> 2) * 128;
  const int n0   = (wv & 3) * 64;

  const int rd0 = wv * 16 + (lane >> 2);
  const int rd1 = 128 + wv * 16 + (lane >> 2);
  const int cs0 = ((lane & 3) - ((rd0 >> 1) & 3)) & 3;
  const int cs1 = ((lane & 3) - ((rd1 >> 1) & 3)) & 3;

  const ushort* gA0 = A  + (size_t)(bm + rd0) * K + cs0 * 8;
  const ushort* gA1 = A  + (size_t)(bm + rd1) * K + cs1 * 8;
  const ushort* gB0 = Bt + (size_t)(bn + rd0) * K + cs0 * 8;
  const ushort* gB1 = Bt + (size_t)(bn + rd1) * K + cs1 * 8;

  auto stageA = [&](int h, int kof) {
    gload16(gA0 + kof, &As[h * 8192 + wv * 512]);
    gload16(gA1 + kof, &As[h * 8192 + (8 + wv) * 512]);
  };
  auto stageB = [&](int h, int kof) {
    gload16(gB0 + kof, &Bs[h * 8192 + wv * 512]);
    gload16(gB1 + kof, &Bs[h * 8192 + (8 + wv) * 512]);
  };

  const int rchunk = ((l4 + ((l16 >> 1) & 3)) & 3) * 8;

  f32x4 acc[8][4];
#pragma unroll
  for (int i = 0; i < 8; ++i)
#pragma unroll
    for (int j = 0; j < 4; ++j) acc[i][j] = (f32x4)0.f;

  const int NT = K >> 6;   // even (20 for K=1280)

  // prologue: tile0 full + tile1 ks0; publish ks0(0)
  stageA(0, 0);  stageB(0, 0);
  stageA(1, 32); stageB(1, 32);
  stageA(2, 64); stageB(2, 64);
  asm volatile("s_waitcnt vmcnt(8)" ::: "memory");
  __builtin_amdgcn_s_barrier();
  FENCE();

  // tile body; db is a literal at each call site -> constant-folded addressing
  auto tileBody = [&](int T, const int db) {
    const int hA = db * 2;
    const int hB = db * 2 + 1;
    short8 a[4], b[4];

    // P0: read hA(lo)+b; stage A-ks1(T+1); MFMA acc[0..3]
#pragma unroll
    for (int i = 0; i < 4; ++i)
      a[i] = *reinterpret_cast<const short8*>(&As[hA * 8192 + (m0 + i * 16 + l16) * 32 + rchunk]);
#pragma unroll
    for (int j = 0; j < 4; ++j)
      b[j] = *reinterpret_cast<const short8*>(&Bs[hA * 8192 + (n0 + j * 16 + l16) * 32 + rchunk]);
    if (T + 1 < NT) stageA((db ^ 1) * 2 + 1, (T + 1) * 64 + 32);
    FENCE(); __builtin_amdgcn_s_barrier(); FENCE();
    __builtin_amdgcn_s_setprio(1);
#pragma unroll
    for (int i = 0; i < 4; ++i)
#pragma unroll
      for (int j = 0; j < 4; ++j)
        acc[i][j] = __builtin_amdgcn_mfma_f32_16x16x32_bf16(a[i], b[j], acc[i][j], 0, 0, 0);
    __builtin_amdgcn_s_setprio(0);
    FENCE(); __builtin_amdgcn_s_barrier(); FENCE();

    // P1: read hA(hi); stage B-ks1(T+1); vmcnt publishes ks1(T); MFMA acc[4..7]
#pragma unroll
    for (int i = 0; i < 4; ++i)
      a[i] = *reinterpret_cast<const short8*>(&As[hA * 8192 + (m0 + 64 + i * 16 + l16) * 32 + rchunk]);
    if (T + 1 < NT) {
      stageB((db ^ 1) * 2 + 1, (T + 1) * 64 + 32);
      asm volatile("s_waitcnt vmcnt(8)" ::: "memory");
    } else {
      asm volatile("s_waitcnt vmcnt(0)" ::: "memory");
    }
    FENCE(); __builtin_amdgcn_s_barrier(); FENCE();
    __builtin_amdgcn_s_setprio(1);
#pragma unroll
    for (int i = 0; i < 4; ++i)
#pragma unroll
      for (int j = 0; j < 4; ++j)
        acc[4 + i][j] = __builtin_amdgcn_mfma_f32_16x16x32_bf16(a[i], b[j], acc[4 + i][j], 0, 0, 0);
    __builtin_amdgcn_s_setprio(0);
    FENCE(); __builtin_amdgcn_s_barrier(); FENCE();

    // P2: read hB(lo)+b; stage A-ks0(T+2) into freed hA; MFMA acc[0..3]
#pragma unroll
    for (int i = 0; i < 4; ++i)
      a[i] = *reinterpret_cast<const short8*>(&As[hB * 8192 + (m0 + i * 16 + l16) * 32 + rchunk]);
#pragma unroll
    for (int j = 0; j < 4; ++j)
      b[j] = *reinterpret_cast<const short8*>(&Bs[hB * 8192 + (n0 + j * 16 + l16) * 32 + rchunk]);
    if (T + 2 < NT) stageA(hA, (T + 2) * 64);
    FENCE(); __builtin_amdgcn_s_barrier(); FENCE();
    __builtin_amdgcn_s_setprio(1);
#pragma unroll
    for (int i = 0; i < 4; ++i)
#pragma unroll
      for (int j = 0; j < 4; ++j)
        acc[i][j] = __builtin_amdgcn_mfma_f32_16x16x32_bf16(a[i], b[j], acc[i][j], 0, 0, 0);
    __builtin_amdgcn_s_setprio(0);
    FENCE(); __builtin_amdgcn_s_barrier(); FENCE();

    // P3: read hB(hi); stage B-ks0(T+2); vmcnt publishes ks0(T+1); MFMA acc[4..7]
#pragma unroll
    for (int i = 0; i < 4; ++i)
      a[i] = *reinterpret_cast<const short8*>(&As[hB * 8192 + (m0 + 64 + i * 16 + l16) * 32 + rchunk]);
    if (T + 2 < NT) {
      stageB(hA, (T + 2) * 64);
      asm volatile("s_waitcnt vmcnt(8)" ::: "memory");
    } else if (T + 1 < NT) {
      asm volatile("s_waitcnt vmcnt(4)" ::: "memory");
    }
    FENCE(); __builtin_amdgcn_s_barrier(); FENCE();
    __builtin_amdgcn_s_setprio(1);
#pragma unroll
    for (int i = 0; i < 4; ++i)
#pragma unroll
      for (int j = 0; j < 4; ++j)
        acc[4 + i][j] = __builtin_amdgcn_mfma_f32_16x16x32_bf16(a[i], b[j], acc[4 + i][j], 0, 0, 0);
    __builtin_amdgcn_s_setprio(0);
    FENCE(); __builtin_amdgcn_s_barrier(); FENCE();
  };

  for (int T = 0; T < NT; T += 2) {
    tileBody(T, 0);
    tileBody(T + 1, 1);
  }

  void* dstv; const float* bias; const float* rs = nullptr; int ldc, cb, relu;
  if (bn < e.nend[0])      { dstv = e.dst[0]; ldc = e.ld[0]; cb = bn;             bias = e.bias[0]; relu = e.relu[0]; rs = e.rs; }
  else if (bn < e.nend[1]) { dstv = e.dst[1]; ldc = e.ld[1]; cb = bn - e.nend[0]; bias = e.bias[1]; relu = e.relu[1]; }
  else if (bn < e.nend[2]) { dstv = e.dst[2]; ldc = e.ld[2]; cb = bn - e.nend[1]; bias = e.bias[2]; relu = e.relu[2]; }
  else if (bn < e.nend[3]) { dstv = e.dst[3]; ldc = e.ld[3]; cb = bn - e.nend[2]; bias = e.bias[3]; relu = e.relu[3]; }
  else                     { dstv = e.dst[4]; ldc = e.ld[4]; cb = bn - e.nend[3]; bias = e.bias[4]; relu = e.relu[4]; }

#pragma unroll
  for (int i = 0; i < 8; ++i) {
    int mbase = bm + m0 + i * 16 + l4 * 4;
    float rsv[4];
#pragma unroll
    for (int r = 0; r < 4; ++r) rsv[r] = rs ? rs[mbase + r] : 1.f;
#pragma unroll
    for (int j = 0; j < 4; ++j) {
      int col = cb + n0 + j * 16 + l16;
      float bv = bias ? bias[col] : 0.f;
#pragma unroll
      for (int r = 0; r < 4; ++r) {
        float t = acc[i][j][r] * rsv[r] + bv;
        if (relu) t = fmaxf(t, 0.f);
        ((ushort*)dstv)[(size_t)(mbase + r) * ldc + col] = f2bf(t);
      }
    }
  }
}

// ---------------- 128x128 bf16 MFMA GEMM (fp2 GEMM; r10-verified ring) ----------------

template<bool F32OUT>
__global__ __launch_bounds__(256) void gemm_bf16(
    const ushort* __restrict__ A, const ushort* __restrict__ Bt, int K, int nb, Epi e)
{
  __shared__ __align__(16) ushort As[3][128 * 32];
  __shared__ __align__(16) ushort Bs[3][128 * 32];

  const int bid = blockIdx.x;
  const int bm  = (bid / nb) * 128;
  const int bn  = (bid % nb) * 128;

  const int tid  = threadIdx.x;
  const int w    = tid >> 6;
  const int lane = tid & 63;
  const int l16  = lane & 15;
  const int l4   = lane >> 4;
  const int m0   = (w >> 1) * 64;
  const int n0   = (w & 1) * 64;

  const int rloc = lane >> 2;
  const int cpos = lane & 3;
  const int cdat = (cpos - (rloc >> 1)) & 3;
  const int srow = w * 32 + rloc;
  const int scol = cdat * 8;

  f32x4 acc[4][4];
#pragma unroll
  for (int i = 0; i < 4; ++i)
#pragma unroll
    for (int j = 0; j < 4; ++j) acc[i][j] = (f32x4)0.f;

  const ushort* pA0 = A  + (size_t)(bm + srow) * K + scol;
  const ushort* pA1 = A  + (size_t)(bm + srow + 16) * K + scol;
  const ushort* pB0 = Bt + (size_t)(bn + srow) * K + scol;
  const ushort* pB1 = Bt + (size_t)(bn + srow + 16) * K + scol;

  auto stage = [&](int buf, int kt) {
    gload16(pA0 + kt, &As[buf][w * 1024]);
    gload16(pA1 + kt, &As[buf][w * 1024 + 512]);
    gload16(pB0 + kt, &Bs[buf][w * 1024]);
    gload16(pB1 + kt, &Bs[buf][w * 1024 + 512]);
  };

  const int rchunk = ((l4 + (l16 >> 1)) & 3) * 8;

  const int nsteps = K >> 5;
  stage(0, 0); stage(1, 32); stage(2, 64);

  for (int t = 0; t < nsteps; ++t) {
    if (t == 0)                asm volatile("s_waitcnt vmcnt(8)" ::: "memory");
    else if (t == nsteps - 1)  asm volatile("s_waitcnt vmcnt(0)" ::: "memory");
    else                       asm volatile("s_waitcnt vmcnt(4)" ::: "memory");
    __builtin_amdgcn_s_barrier();
    FENCE();

    if (t >= 1 && t + 2 < nsteps) stage((t + 2) % 3, (t + 2) * 32);

    const int cur = t % 3;
    short8 a[4], b[4];
#pragma unroll
    for (int i = 0; i < 4; ++i)
      a[i] = *reinterpret_cast<const short8*>(&As[cur][(m0 + i * 16 + l16) * 32 + rchunk]);
#pragma unroll
    for (int j = 0; j < 4; ++j)
      b[j] = *reinterpret_cast<const short8*>(&Bs[cur][(n0 + j * 16 + l16) * 32 + rchunk]);
    __builtin_amdgcn_s_setprio(1);
#pragma unroll
    for (int i = 0; i < 4; ++i)
#pragma unroll
      for (int j = 0; j < 4; ++j)
        acc[i][j] = __builtin_amdgcn_mfma_f32_16x16x32_bf16(a[i], b[j], acc[i][j], 0, 0, 0);
    __builtin_amdgcn_s_setprio(0);
  }

  void* dstv; const float* bias; const float* rs = nullptr; int ldc, cb, relu;
  if (bn < e.nend[0])      { dstv = e.dst[0]; ldc = e.ld[0]; cb = bn;             bias = e.bias[0]; relu = e.relu[0]; rs = e.rs; }
  else if (bn < e.nend[1]) { dstv = e.dst[1]; ldc = e.ld[1]; cb = bn - e.nend[0]; bias = e.bias[1]; relu = e.relu[1]; }
  else if (bn < e.nend[2]) { dstv = e.dst[2]; ldc = e.ld[2]; cb = bn - e.nend[1]; bias = e.bias[2]; relu = e.relu[2]; }
  else if (bn < e.nend[3]) { dstv = e.dst[3]; ldc = e.ld[3]; cb = bn - e.nend[2]; bias = e.bias[3]; relu = e.relu[3]; }
  else                     { dstv = e.dst[4]; ldc = e.ld[4]; cb = bn - e.nend[3]; bias = e.bias[4]; relu = e.relu[4]; }

#pragma unroll
  for (int i = 0; i < 4; ++i) {
    int mbase = bm + m0 + i * 16 + l4 * 4;
    float rsv[4];
#pragma unroll
    for (int r = 0; r < 4; ++r) rsv[r] = rs ? rs[mbase + r] : 1.f;
#pragma unroll
    for (int j = 0; j < 4; ++j) {
      int col = cb + n0 + j * 16 + l16;
      float bv = bias ? bias[col] : 0.f;
#pragma unroll
      for (int r = 0; r < 4; ++r) {
        float t = acc[i][j][r] * rsv[r] + bv;
        if (relu) t = fmaxf(t, 0.f);
        if (F32OUT) ((float*)dstv)[(size_t)(mbase + r) * ldc + col] = t;
        else        ((ushort*)dstv)[(size_t)(mbase + r) * ldc + col] = f2bf(t);
      }
    }
  }
}

// ---------------- pwprep: softmax rows + prefix-mean rows -> global pc (f32) ----------------

__global__ __launch_bounds__(256) void pwprep_kernel(
    const float* __restrict__ fp2, const float* __restrict__ fp_b2,
    float* __restrict__ pc)
{
  int b = blockIdx.x;
  int tid = threadIdx.x, wv = tid >> 6, lane = tid & 63;
  __shared__ float pws[S][S];
  for (int i = wv; i < S; i += 4) {
    float v = (lane < S) ? (fp2[(size_t)(b * S + i) * 128 + lane] + fp_b2[lane]) : -1e30f;
    float m = v;
#pragma unroll
    for (int off = 32; off; off >>= 1) m = fmaxf(m, __shfl_xor(m, off));
    float e = (lane < S) ? expf(v - m) : 0.f;
    float sum = e;
#pragma unroll
    for (int off = 32; off; off >>= 1) sum += __shfl_xor(sum, off);
    if (lane < S) {
      float p = e / sum;
      pws[i][lane] = p;
      pc[((size_t)b * S + i) * 128 + lane] = p;
    }
  }
  __syncthreads();
  if (tid < S) {
    float run = 0.f;
    for (int i = 0; i < S; ++i) {
      pc[((size_t)b * S + i) * 128 + 64 + tid] = (i > 0) ? run / (float)i : 0.f;
      run += pws[i][tid];
    }
  }
}

// ---------------- mixc: sage = P@xr + CPW@xl + bl, coefficients via wave-uniform s_load ----------------

__global__ __launch_bounds__(256) void mixc_kernel(
    const float* __restrict__ pc, const ushort* __restrict__ xr,
    const ushort* __restrict__ xl, const float* __restrict__ sage_bl,
    ushort* __restrict__ hbuf)
{
  int b  = blockIdx.y;
  int d0 = blockIdx.x * 256;    // grid.x = DOUT/256 = 4
  int tid = threadIdx.x;

  float xrv[S], xlv[S];
  const ushort* xrp = xr + (size_t)(b * S) * DOUT + d0 + tid;
  const ushort* xlp = xl + (size_t)(b * S) * DOUT + d0 + tid;
#pragma unroll
  for (int j = 0; j < S; ++j) {
    xrv[j] = bf2f(xrp[(size_t)j * DOUT]);
    xlv[j] = bf2f(xlp[(size_t)j * DOUT]);
  }
  float bl = sage_bl[d0 + tid];
  ushort* op = hbuf + (size_t)(b * S) * DOUT + d0 + tid;
  const float* pcb = pc + (size_t)(b * S) * 128;
  for (int i = 0; i < S; ++i) {
    const float* row = pcb + (size_t)i * 128;   // wave-uniform -> s_load path
    float acc = bl;
#pragma unroll
    for (int j = 0; j < S; ++j)
      acc += row[j] * xrv[j] + row[64 + j] * xlv[j];
    op[(size_t)i * DOUT] = f2bf(acc);
  }
}

// ---------------- fused tail (single-sync, parity-buffered reductions) ----------------

__device__ __forceinline__ float dinv_local(int j) {
  return rsqrtf((j == 0 || j == S - 1) ? 3.f : 5.f);
}

__global__ __launch_bounds__(256) void tail_fused(
    const ushort* __restrict__ gcnh, const ushort* __restrict__ Cgat,
    const ushort* __restrict__ hbuf,
    const float* __restrict__ gcn_b, const float* __restrict__ sn_g, const float* __restrict__ sn_b,
    const float* __restrict__ gat_as, const float* __restrict__ gat_ad, const float* __restrict__ gat_b,
    const float* __restrict__ mn_g, const float* __restrict__ mn_b,
    const float* __restrict__ dn_g, const float* __restrict__ dn_b,
    const float* __restrict__ gw, const float* __restrict__ gb,
    float* __restrict__ out, int N)
{
  int b  = blockIdx.x >> 2;
  int rb = blockIdx.x & 3;
  int lo = rb * 13;
  int cnt = (rb < 3) ? 13 : 2;
  size_t OUT = (size_t)N * DOUT;
  int tid = threadIdx.x;
  int wv = tid >> 6, lane = tid & 63;
  int d0 = tid * 4;
  int head = tid >> 6;

  __shared__ __align__(16) ushort hs[13][DOUT];
  __shared__ float alpha[13][13][HEADS];
  __shared__ float als_l[13][HEADS], ald_l[13][HEADS];
  __shared__ float red6[2][6][4];     // parity-buffered: 1 sync per reduction
  __shared__ float red3[2][3][4];

  for (int r = 0; r < cnt; ++r) {
    const ushort4* src = (const ushort4*)(Cgat + (size_t)(b * S + lo + r) * DOUT);
    ((ushort4*)hs[r])[tid] = src[tid];
  }
  __syncthreads();

  {
    const float4* a4 = (const float4*)(gat_as + wv * HC);
    const float4* d4 = (const float4*)(gat_ad + wv * HC);
    float4 av = a4[lane], dv = d4[lane];
    for (int s = 0; s < cnt; ++s) {
      ushort4 hv4 = ((const ushort4*)&hs[s][wv * HC])[lane];
      float h0 = bf2f(hv4.x), h1 = bf2f(hv4.y), h2 = bf2f(hv4.z), h3 = bf2f(hv4.w);
      float a = h0 * av.x + h1 * av.y + h2 * av.z + h3 * av.w;
      float d = h0 * dv.x + h1 * dv.y + h2 * dv.z + h3 * dv.w;
      a = warpReduceSum(a);
      d = warpReduceSum(d);
      if (lane == 0) { als_l[s][wv] = a; ald_l[s][wv] = d; }
    }
  }
  __syncthreads();

  if (tid < cnt * HEADS) {
    int t = tid >> 2, hd = tid & 3;
    float myald = ald_l[t][hd];
    float m = -1e30f;
    for (int s = 0; s < cnt; ++s) {
      float v = als_l[s][hd] + myald;
      v = (v > 0.f) ? v : 0.2f * v;
      m = fmaxf(m, v);
    }
    float den = 0.f;
    for (int s = 0; s < cnt; ++s) {
      float v = als_l[s][hd] + myald;
      v = (v > 0.f) ? v : 0.2f * v;
      float ev = expf(v - m) * ((s == t) ? 1.f : 2.f);  // duplicate edges -> weight 2
      alpha[t][s][hd] = ev;
      den += ev;
    }
    float inv = 1.f / den;
    for (int s = 0; s < cnt; ++s) alpha[t][s][hd] *= inv;
  }
  __syncthreads();

  float4 gcnb4 = *(const float4*)(gcn_b + d0);
  float4 sng4  = *(const float4*)(sn_g + d0);
  float4 snb4  = *(const float4*)(sn_b + d0);
  float4 gatb4 = *(const float4*)(gat_b + d0);
  float4 mng4  = *(const float4*)(mn_g + d0);
  float4 mnb4  = *(const float4*)(mn_b + d0);
  float4 dng4  = *(const float4*)(dn_g + d0);
  float4 dnb4  = *(const float4*)(dn_b + d0);
  float gwsh[4][3], gwga[4][3], gwsa[4][3];
#pragma unroll
  for (int q = 0; q < 4; ++q)
#pragma unroll
    for (int c = 0; c < 3; ++c) {
      gwsh[q][c] = gw[(size_t)(d0 + q) * 3 + c];
      gwga[q][c] = gw[(size_t)(DOUT + d0 + q) * 3 + c];
      gwsa[q][c] = gw[(size_t)(2 * DOUT + d0 + q) * 3 + c];
    }

  for (int t = 0; t < cnt; ++t) {
    int i = lo + t;
    size_t n = (size_t)(b * S + i);
    int par = t & 1;

    float di = dinv_local(i);
    float wc = di * di;
    float wl = (i > 0)     ? 2.f * di * dinv_local(i - 1) : 0.f;
    float wr = (i < S - 1) ? 2.f * di * dinv_local(i + 1) : 0.f;
    const ushort* hc = gcnh + n * DOUT + d0;
    ushort4 c4  = *(const ushort4*)hc;
    ushort4 lft = (i > 0)     ? *(const ushort4*)(hc - DOUT) : ushort4{0, 0, 0, 0};
    ushort4 rgt = (i < S - 1) ? *(const ushort4*)(hc + DOUT) : ushort4{0, 0, 0, 0};
    const ushort* cp = (const ushort*)&c4;
    const ushort* lp = (const ushort*)&lft;
    const ushort* rp = (const ushort*)&rgt;
    const float* gbp = (const float*)&gcnb4;
    float sh[4];
#pragma unroll
    for (int q = 0; q < 4; ++q)
      sh[q] = wc * bf2f(cp[q]) + wl * bf2f(lp[q]) + wr * bf2f(rp[q]) + gbp[q];

    float ga[4] = {0.f, 0.f, 0.f, 0.f};
    for (int si = 0; si < cnt; ++si) {
      float aj = alpha[t][si][head];
      ushort4 hv = *(const ushort4*)&hs[si][d0];
      ga[0] += aj * bf2f(hv.x);
      ga[1] += aj * bf2f(hv.y);
      ga[2] += aj * bf2f(hv.z);
      ga[3] += aj * bf2f(hv.w);
    }
    const float* gab = (const float*)&gatb4;
#pragma unroll
    for (int q = 0; q < 4; ++q) ga[q] += gab[q];

    ushort4 s4v = *(const ushort4*)(hbuf + n * DOUT + d0);
    const ushort* sp = (const ushort*)&s4v;
    float sa[4];
#pragma unroll
    for (int q = 0; q < 4; ++q) sa[q] = bf2f(sp[q]);

    float red[6] = {0.f, 0.f, 0.f, 0.f, 0.f, 0.f};
#pragma unroll
    for (int q = 0; q < 4; ++q) {
      red[0] += sh[q]; red[1] += sh[q] * sh[q];
      red[2] += ga[q]; red[3] += ga[q] * ga[q];
      red[4] += sa[q]; red[5] += sa[q] * sa[q];
    }
#pragma unroll
    for (int r = 0; r < 6; ++r) red[r] = warpReduceSum(red[r]);
    if (lane == 0) {
#pragma unroll
      for (int r = 0; r < 6; ++r) red6[par][r][wv] = red[r];
    }
    __syncthreads();
#pragma unroll
    for (int r = 0; r < 6; ++r)
      red[r] = red6[par][r][0] + red6[par][r][1] + red6[par][r][2] + red6[par][r][3];

    float mu0 = red[0] * (1.f / DOUT), r0 = rsqrtf(red[1] * (1.f / DOUT) - mu0 * mu0 + 1e-5f);
    float mu1 = red[2] * (1.f / DOUT), r1 = rsqrtf(red[3] * (1.f / DOUT) - mu1 * mu1 + 1e-5f);
    float mu2 = red[4] * (1.f / DOUT), r2 = rsqrtf(red[5] * (1.f / DOUT) - mu2 * mu2 + 1e-5f);

    const float* sngp = (const float*)&sng4; const float* snbp = (const float*)&snb4;
    const float* mngp = (const float*)&mng4; const float* mnbp = (const float*)&mnb4;
    const float* dngp = (const float*)&dng4; const float* dnbp = (const float*)&dnb4;
    float shn[4], gan[4], san[4];
#pragma unroll
    for (int q = 0; q < 4; ++q) {
      shn[q] = (sh[q] - mu0) * r0 * sngp[q] + snbp[q];
      gan[q] = (ga[q] - mu1) * r1 * mngp[q] + mnbp[q];
      san[q] = (sa[q] - mu2) * r2 * dngp[q] + dnbp[q];
    }

    float p[3] = {0.f, 0.f, 0.f};
#pragma unroll
    for (int q = 0; q < 4; ++q) {
#pragma unroll
      for (int c = 0; c < 3; ++c)
        p[c] += shn[q] * gwsh[q][c] + gan[q] * gwga[q][c] + san[q] * gwsa[q][c];
    }
#pragma unroll
    for (int r = 0; r < 3; ++r) p[r] = warpReduceSum(p[r]);
    if (lane == 0) {
#pragma unroll
      for (int r = 0; r < 3; ++r) red3[par][r][wv] = p[r];
    }
    __syncthreads();
#pragma unroll
    for (int r = 0; r < 3; ++r)
      p[r] = red3[par][r][0] + red3[par][r][1] + red3[par][r][2] + red3[par][r][3];

    float l0 = p[0] + gb[0], l1 = p[1] + gb[1], l2 = p[2] + gb[2];
    float m = fmaxf(l0, fmaxf(l1, l2));
    float e0 = expf(l0 - m), e1 = expf(l1 - m), e2 = expf(l2 - m);
    float inv = 1.f / (e0 + e1 + e2);
    float g0 = e0 * inv, g1 = e1 * inv, g2 = e2 * inv;

    float4 o0, o1, o2;
    float* o0p = (float*)&o0; float* o1p = (float*)&o1; float* o2p = (float*)&o2;
#pragma unroll
    for (int q = 0; q < 4; ++q) {
      o0p[q] = shn[q];
      o1p[q] = gan[q];
      o2p[q] = g0 * shn[q] + g1 * gan[q] + g2 * san[q];
    }
    *(float4*)(out + n * DOUT + d0)           = o0;
    *(float4*)(out + OUT + n * DOUT + d0)     = o1;
    *(float4*)(out + 2 * OUT + n * DOUT + d0) = o2;
  }
}

// ---------------- launch ----------------

extern "C" void kernel_launch(void* const* d_in, const int* in_sizes, int n_in,
                              void* d_out, int out_size, void* d_ws, size_t ws_size,
                              hipStream_t stream) {
  const float* x       = (const float*)d_in[0];
  const float* att_w   = (const float*)d_in[1];
  const float* att_b   = (const float*)d_in[2];
  const float* gcn_w   = (const float*)d_in[3];
  const float* gcn_b   = (const float*)d_in[4];
  const float* sn_g    = (const float*)d_in[5];
  const float* sn_b    = (const float*)d_in[6];
  const float* gat_w   = (const float*)d_in[7];
  const float* gat_as  = (const float*)d_in[8];
  const float* gat_ad  = (const float*)d_in[9];
  const float* gat_b   = (const float*)d_in[10];
  const float* mn_g    = (const float*)d_in[11];
  const float* mn_b    = (const float*)d_in[12];
  const float* sage_wl = (const float*)d_in[13];
  const float* sage_bl = (const float*)d_in[14];
  const float* sage_wr = (const float*)d_in[15];
  const float* fp_w1   = (const float*)d_in[16];
  const float* fp_b1   = (const float*)d_in[17];
  const float* fp_w2   = (const float*)d_in[18];
  const float* fp_b2   = (const float*)d_in[19];
  const float* dn_g    = (const float*)d_in[20];
  const float* dn_b    = (const float*)d_in[21];
  const float* gate_w  = (const float*)d_in[22];
  const float* gate_b  = (const float*)d_in[23];

  const int B = in_sizes[0] / (S * DIN);   // 512
  const int N = B * S;                     // 20992 = 82*256
  const int MB  = N / 128;                 // 164 (fp2 GEMM)
  const int MB2 = N / 256;                 // 82  (mega GEMM)
  const int NMEGA = 4608;                  // [gcn 1024 | gat 1024 | fp1 512 | xr 1024 | xl 1024]
  float* out = (float*)d_out;

  char* ws = (char*)d_ws;
  size_t off = 0;
  auto alloc = [&](size_t bytes) { size_t p = off; off += (bytes + 255) & ~(size_t)255; return p; };
  ushort* xb   = (ushort*)(ws + alloc((size_t)N * DIN * 2));       // 53.7 MB
  ushort* Bt   = (ushort*)(ws + alloc((size_t)NMEGA * DIN * 2));   // 11.8 MB
  ushort* wpw  = (ushort*)(ws + alloc((size_t)128 * 512 * 2));     // 0.13 MB
  ushort* gcnh = (ushort*)(ws + alloc((size_t)N * DOUT * 2));      // 43 MB
  ushort* Cgat = (ushort*)(ws + alloc((size_t)N * DOUT * 2));      // 43 MB
  ushort* xr   = (ushort*)(ws + alloc((size_t)N * DOUT * 2));      // 43 MB
  ushort* xl   = (ushort*)(ws + alloc((size_t)N * DOUT * 2));      // 43 MB
  ushort* hbuf = (ushort*)(ws + alloc((size_t)N * DOUT * 2));      // 43 MB (fp1 aliases; mixc overwrites)
  float*  fp2  = (float*)(ws + alloc((size_t)N * 128 * 4));        // 10.7 MB
  float*  pc   = (float*)(ws + alloc((size_t)N * 128 * 4));        // 10.7 MB
  float*  sig  = (float*)(ws + alloc((size_t)N * 4));
  ushort* fp1  = hbuf;   // fp1 (N x 512 bf16) dead after fp2 GEMM; mixc then overwrites as hbuf

  dim3 blk(256);

  // converts + sigmoid gate (6 -> 3 convert launches)
  cvtsig_kernel<<<N / 4, blk, 0, stream>>>((const float4*)x, att_w, att_b, (ushort4*)xb, sig);
  W4 w4;
  w4.src[0] = gcn_w;  w4.dst[0] = Bt;
  w4.src[1] = gat_w;  w4.dst[1] = Bt + (size_t)1024 * DIN;
  w4.src[2] = sage_wr; w4.dst[2] = Bt + (size_t)2560 * DIN;
  w4.src[3] = sage_wl; w4.dst[3] = Bt + (size_t)3584 * DIN;
  wcvt4_kernel<<<dim3(DOUT / 32, DIN / 32, 4), blk, 0, stream>>>(w4);
  wcvt_kernel<<<dim3(512 / 32, DIN / 32), blk, 0, stream>>>(fp_w1, Bt + (size_t)2048 * DIN, DIN, 512, DIN, 0);
  w2cvt_kernel<<<dim3(128 * 512 / 256), blk, 0, stream>>>(fp_w2, wpw);

  // mega-GEMM (8-phase 256^2, m201 phase order + XCD swizzle, T-unrolled)
  Epi e1;
  e1.dst[0] = gcnh; e1.dst[1] = Cgat; e1.dst[2] = fp1; e1.dst[3] = xr; e1.dst[4] = xl;
  e1.bias[0] = nullptr; e1.bias[1] = nullptr; e1.bias[2] = fp_b1; e1.bias[3] = nullptr; e1.bias[4] = nullptr;
  e1.nend[0] = 1024; e1.nend[1] = 2048; e1.nend[2] = 2560; e1.nend[3] = 3584; e1.nend[4] = 4608;
  e1.ld[0] = DOUT; e1.ld[1] = DOUT; e1.ld[2] = 512; e1.ld[3] = DOUT; e1.ld[4] = DOUT;
  e1.relu[0] = 0; e1.relu[1] = 0; e1.relu[2] = 1; e1.relu[3] = 0; e1.relu[4] = 0;
  e1.rs = sig;
  gemm8p<<<dim3(MB2 * (NMEGA / 256)), dim3(512), 0, stream>>>(xb, Bt, DIN, NMEGA / 256, e1);

  // fp2 logits GEMM (N=128 padded) — 128^2 ring kernel
  Epi epw;
  epw.dst[0] = fp2; epw.dst[1] = nullptr; epw.dst[2] = nullptr; epw.dst[3] = nullptr; epw.dst[4] = nullptr;
  epw.bias[0] = nullptr; epw.bias[1] = nullptr; epw.bias[2] = nullptr; epw.bias[3] = nullptr; epw.bias[4] = nullptr;
  epw.nend[0] = 1 << 30; epw.nend[1] = 1 << 30; epw.nend[2] = 1 << 30; epw.nend[3] = 1 << 30; epw.nend[4] = 1 << 30;
  epw.ld[0] = 128; epw.ld[1] = 128; epw.ld[2] = 128; epw.ld[3] = 128; epw.ld[4] = 128;
  epw.relu[0] = 0; epw.relu[1] = 0; epw.relu[2] = 0; epw.relu[3] = 0; epw.relu[4] = 0;
  epw.rs = nullptr;
  gemm_bf16<true><<<dim3(MB), blk, 0, stream>>>(fp1, wpw, 512, 1, epw);

  // deep combine: softmax+prefix coefficients -> pc (global), then s_load-driven mixing
  pwprep_kernel<<<B, blk, 0, stream>>>(fp2, fp_b2, pc);
  mixc_kernel<<<dim3(DOUT / 256, B), blk, 0, stream>>>(pc, xr, xl, sage_bl, hbuf);

  // fused tail: all three branches + gate -> out0/out1/out2
  tail_fused<<<B * 4, blk, 0, stream>>>(gcnh, Cgat, hbuf,
                                        gcn_b, sn_g, sn_b,
                                        gat_as, gat_ad, gat_b,
                                        mn_g, mn_b, dn_g, dn_b,
                                        gate_w, gate_b, out, N);
}